// Round 9
// baseline (288.163 us; speedup 1.0000x reference)
//
#include <hip/hip_runtime.h>
#include <math.h>

#define B_SZ    2
#define L_SEQ   1024
#define DMODEL  1024
#define DINNER  2048
#define DSTATE  16
#define EPSV    1e-6f

// scan decomposition: 16 channels/block, 64 chunks of 16 steps, 1024 thr/block
#define CCH 64
#define CS  (L_SEQ / CCH)      // 16
#define DT  16
#define SSTR 1040              // CCH*DT + 16 (520 dwords == 8 mod 32, conflict-free combine)

typedef short  bf16x8  __attribute__((ext_vector_type(8)));
typedef float  floatx4 __attribute__((ext_vector_type(4)));
typedef unsigned short ushort8v __attribute__((ext_vector_type(8)));

extern "C" __device__ float __ocml_native_exp2_f32(float);
extern "C" __device__ float __ocml_native_log2_f32(float);

__device__ __forceinline__ float nexp2(float x) { return __ocml_native_exp2_f32(x); }

__device__ __forceinline__ float softplus_f(float v) {
    if (v > 20.f) return v;
    return 0.69314718f * __ocml_native_log2_f32(1.f + nexp2(v * 1.44269504f));
}
__device__ __forceinline__ float silu_f(float z) {
    return z / (1.f + nexp2(z * -1.44269504f));
}

__device__ __forceinline__ unsigned short f2bf(float f) {
    unsigned int u = __float_as_uint(f);
    unsigned int r = (u + 0x7FFFu + ((u >> 16) & 1u)) >> 16;
    return (unsigned short)r;
}
__device__ __forceinline__ float bf2f(unsigned short u) {
    return __uint_as_float(((unsigned int)u) << 16);
}

// async global->LDS, 16 B per lane. LDS dest = wave-uniform base + lane*16.
__device__ __forceinline__ void gload_lds16(const unsigned short* g, unsigned short* l) {
    __builtin_amdgcn_global_load_lds(
        (const __attribute__((address_space(1))) unsigned int*)g,
        (__attribute__((address_space(3))) unsigned int*)l,
        16, 0, 0);
}

// ---------------------------------------------------------------------------
// Prep: 3 weight transposes (+cast). x cast now folded into gemm1 (AF32).
// ---------------------------------------------------------------------------
__global__ __launch_bounds__(256) void prep_kernel(
    const float* __restrict__ W_in, unsigned short* __restrict__ W_in_t,
    const float* __restrict__ W_dt, unsigned short* __restrict__ W_dt_t,
    const float* __restrict__ W_out, unsigned short* __restrict__ W_out_t)
{
    const int bid = blockIdx.x;
    __shared__ float tile[32][33];
    const float* W; unsigned short* Wt; int K, N, t;
    if (bid < 4096)      { W = W_in;  Wt = W_in_t;  K = 1024; N = 4096; t = bid; }
    else if (bid < 8192) { W = W_dt;  Wt = W_dt_t;  K = 2048; N = 2048; t = bid - 4096; }
    else                 { W = W_out; Wt = W_out_t; K = 2048; N = 1024; t = bid - 8192; }
    const int nx = N >> 5;
    const int n0 = (t % nx) * 32;
    const int k0 = (t / nx) * 32;
    const int c = threadIdx.x & 31;
    const int r = threadIdx.x >> 5;
#pragma unroll
    for (int i = 0; i < 4; ++i)
        tile[r + 8 * i][c] = W[(size_t)(k0 + r + 8 * i) * N + n0 + c];
    __syncthreads();
#pragma unroll
    for (int i = 0; i < 4; ++i)
        Wt[(size_t)(n0 + r + 8 * i) * K + k0 + c] = f2bf(tile[c][r + 8 * i]);
}

// ---------------------------------------------------------------------------
// bf16 MFMA GEMM. B (and A when bf16) staged via global_load_lds width-16
// with swizzle folded into the per-lane global address (LDS stays linear,
// image identical to the proven reg-staged layout). AF32: A is f32, staged
// through registers with inline f2bf cast (kills the separate x-cast pass).
// NGEMM != 0: 1D grid; blocks >= NGEMM do a 64x64 bf16 transpose
// (tin [M][D] -> tout [D][M]) reusing As as the LDS tile — folds the old
// transp_bf16 kernel into this launch.
// MODE 0: +bias; 1: softplus(+bias); 2: +bias+resid;
// 4: softplus(+bias) -> bf16 transposed Ct[col][row];
// 5: split: cols<DINNER -> f32 C; cols>=DINNER -> silu -> bf16 zout^T.
// ---------------------------------------------------------------------------
template <int TM, int TN, int MODE, int MINW, bool AF32, int NGEMM>
__global__ __launch_bounds__(256, MINW) void gemm_bf16(
    const void* __restrict__ Araw, const unsigned short* __restrict__ Bt,
    const float* __restrict__ bias, const float* __restrict__ resid,
    float* __restrict__ C, unsigned short* __restrict__ zout,
    const unsigned short* __restrict__ tin, unsigned short* __restrict__ tout,
    int M, int N, int K)
{
    constexpr int MI = TM / 32;
    constexpr int NJ = TN / 32;
    constexpr int NI  = (AF32 ? TN : TM + TN) / 32;  // gload instrs per wave
    constexpr int ASL = AF32 ? TM / 32 : 0;          // reg-staged A slots

    __shared__ unsigned short As[TM * 64];
    __shared__ unsigned short Bs[TN * 64];

    const int tid  = threadIdx.x;

    if (NGEMM != 0 && (int)blockIdx.x >= NGEMM) {
        // ---- transpose block: tin [M][DINNER] -> tout [DINNER][M] ----
        unsigned short (*tile)[66] = (unsigned short (*)[66])As;  // 8.4 KB <= As
        const int t = blockIdx.x - NGEMM;
        const int m0t = (t & 31) * 64;
        const int d0t = (t >> 5) * 64;
        const int r = tid >> 3;
        const int c = (tid & 7) * 8;
#pragma unroll
        for (int i = 0; i < 2; ++i) {
            const int row = r + i * 32;
            ushort8v v = *(const ushort8v*)&tin[(size_t)(m0t + row) * DINNER + d0t + c];
            *(ushort8v*)&tile[row][c] = v;
        }
        __syncthreads();
#pragma unroll
        for (int i = 0; i < 2; ++i) {
            const int dd = r + i * 32;
            ushort8v o;
#pragma unroll
            for (int k = 0; k < 8; ++k) o[k] = tile[c + k][dd];
            *(ushort8v*)&tout[(size_t)(d0t + dd) * (B_SZ * L_SEQ) + m0t + c] = o;
        }
        return;
    }

    const int wave = tid >> 6;
    const int lane = tid & 63;
    const int nx = N / TN;
    const int m0 = (NGEMM != 0 ? (int)blockIdx.x / nx : (int)blockIdx.y) * TM;
    const int n0 = (NGEMM != 0 ? (int)blockIdx.x % nx : (int)blockIdx.x) * TN;
    const int wm = (wave >> 1) * (TM / 2);
    const int wn = (wave & 1) * (TN / 2);
    const int fr = lane & 15;
    const int kg = lane >> 4;

    // per-wave gload descriptors (B always; A too when bf16)
    const unsigned short* gq[NI];
    unsigned short* lq[NI];
#pragma unroll
    for (int q = 0; q < NI; ++q) {
        const int r0i = (wave * NI + q) * 8;
        const int sub = lane >> 3;
        const int pos = lane & 7;
        const int rA  = AF32 ? (TM + r0i) : r0i;   // virtual row in [A|B] space
        if (rA < TM) {
            const int row = rA + sub;
            const int ch  = pos ^ (row & 7);
            gq[q] = (const unsigned short*)Araw + (size_t)(m0 + row) * K + ch * 8;
            lq[q] = &As[rA * 64];
        } else {
            const int rb = rA - TM + sub;
            const int ch = pos ^ (rb & 7);
            gq[q] = Bt + (size_t)(n0 + rb) * K + ch * 8;
            lq[q] = &Bs[(rA - TM) * 64];
        }
    }

    // per-thread reg-staged A descriptors (AF32 only)
    int offsA[ASL ? ASL : 1];
    unsigned short* lpA[ASL ? ASL : 1];
    if (AF32) {
#pragma unroll
        for (int i = 0; i < ASL; ++i) {
            const int slot = i * 256 + tid;
            const int row  = slot >> 3;
            const int ch   = slot & 7;
            const int pos  = ch ^ (row & 7);
            offsA[i] = (m0 + row) * K + ch * 8;
            lpA[i]   = &As[row * 64 + pos * 8];
        }
    }

    auto stage = [&](int kt) {
#pragma unroll
        for (int q = 0; q < NI; ++q) gload_lds16(gq[q] + kt, lq[q]);
        if (AF32) {
            const float* Af = (const float*)Araw;
#pragma unroll
            for (int i = 0; i < ASL; ++i) {
                float4 a0 = *(const float4*)(Af + offsA[i] + kt);
                float4 a1 = *(const float4*)(Af + offsA[i] + kt + 4);
                ushort8v o = { f2bf(a0.x), f2bf(a0.y), f2bf(a0.z), f2bf(a0.w),
                               f2bf(a1.x), f2bf(a1.y), f2bf(a1.z), f2bf(a1.w) };
                *(ushort8v*)lpA[i] = o;
            }
        }
    };

    floatx4 acc[MI][NJ] = {};

    stage(0);

    for (int kt = 0; kt < K; kt += 64) {
        __syncthreads();   // drains vmcnt (gload) + lgkm (A writes)

#pragma unroll
        for (int ks = 0; ks < 2; ++ks) {
            const int cq = (ks << 2) | kg;
            bf16x8 af[MI], bfv[NJ];
#pragma unroll
            for (int i = 0; i < MI; ++i) {
                const int row = wm + i * 16 + fr;
                af[i] = *(const bf16x8*)&As[row * 64 + ((cq ^ (row & 7)) << 3)];
            }
#pragma unroll
            for (int j = 0; j < NJ; ++j) {
                const int row = wn + j * 16 + fr;
                bfv[j] = *(const bf16x8*)&Bs[row * 64 + ((cq ^ (row & 7)) << 3)];
            }
#pragma unroll
            for (int i = 0; i < MI; ++i)
#pragma unroll
                for (int j = 0; j < NJ; ++j)
                    acc[i][j] = __builtin_amdgcn_mfma_f32_16x16x32_bf16(
                        af[i], bfv[j], acc[i][j], 0, 0, 0);
        }

        if (kt + 64 < K) {
            __syncthreads();   // all reads done before overwrite
            stage(kt + 64);
        }
    }

    const int rq = (lane >> 4) * 4;
    if (MODE == 4) {
        unsigned short* Ct = (unsigned short*)C;
#pragma unroll
        for (int i = 0; i < MI; ++i) {
#pragma unroll
            for (int j = 0; j < NJ; ++j) {
                const int col = n0 + wn + j * 16 + fr;
                const float bv = bias[col];
                const int row0 = m0 + wm + i * 16 + rq;
                ushort4 o;
#pragma unroll
                for (int r = 0; r < 4; ++r)
                    (&o.x)[r] = f2bf(softplus_f(acc[i][j][r] + bv));
                *(ushort4*)&Ct[(size_t)col * M + row0] = o;
            }
        }
    } else if (MODE == 5) {
        if (n0 < DINNER) {
#pragma unroll
            for (int i = 0; i < MI; ++i) {
#pragma unroll
                for (int j = 0; j < NJ; ++j) {
                    const int col = n0 + wn + j * 16 + fr;
                    const float bv = bias[col];
#pragma unroll
                    for (int r = 0; r < 4; ++r) {
                        const int row = m0 + wm + i * 16 + rq + r;
                        C[(size_t)row * DINNER + col] = acc[i][j][r] + bv;
                    }
                }
            }
        } else {
#pragma unroll
            for (int i = 0; i < MI; ++i) {
#pragma unroll
                for (int j = 0; j < NJ; ++j) {
                    const int col = n0 + wn + j * 16 + fr;
                    const float bv = bias[col];
                    const int row0 = m0 + wm + i * 16 + rq;
                    ushort4 o;
#pragma unroll
                    for (int r = 0; r < 4; ++r)
                        (&o.x)[r] = f2bf(silu_f(acc[i][j][r] + bv));
                    *(ushort4*)&zout[(size_t)(col - DINNER) * M + row0] = o;
                }
            }
        }
    } else {
#pragma unroll
        for (int i = 0; i < MI; ++i) {
#pragma unroll
            for (int j = 0; j < NJ; ++j) {
                const int col = n0 + wn + j * 16 + fr;
                const float bv = bias[col];
#pragma unroll
                for (int r = 0; r < 4; ++r) {
                    const int row = m0 + wm + i * 16 + rq + r;
                    float v = acc[i][j][r] + bv;
                    if (MODE == 1) {
                        v = softplus_f(v);
                    } else if (MODE == 2) {
                        v += resid[(size_t)row * N + col];
                    }
                    C[(size_t)row * N + col] = v;
                }
            }
        }
    }
}

// ---------------------------------------------------------------------------
// Fused depthwise causal conv1d(k=4) + SiLU + x_proj. bf16 x_conv only.
// ---------------------------------------------------------------------------
#define CROWS 4
__global__ __launch_bounds__(256) void conv_xproj(
    const float* __restrict__ x_in, const float* __restrict__ conv_w,
    const float* __restrict__ conv_b, const float* __restrict__ W_xp,
    const float* __restrict__ b_xp,
    unsigned short* __restrict__ x_conv_bf, float* __restrict__ BC)
{
    __shared__ float sxc[CROWS][DINNER];   // 32 KB
    __shared__ float red[8][CROWS][32];    // 4 KB

    const int tid = threadIdx.x;
    const int r0 = blockIdx.x * CROWS;
    const int c8 = tid * 8;

    float wt[8][4];
#pragma unroll
    for (int ci = 0; ci < 8; ++ci) {
        float4 w4 = *(const float4*)&conv_w[(c8 + ci) * 4];
        wt[ci][0] = w4.x; wt[ci][1] = w4.y; wt[ci][2] = w4.z; wt[ci][3] = w4.w;
    }
    float cb[8];
    *(float4*)&cb[0] = *(const float4*)&conv_b[c8];
    *(float4*)&cb[4] = *(const float4*)&conv_b[c8 + 4];

#pragma unroll
    for (int rr = 0; rr < CROWS; ++rr) {
        const int row = r0 + rr;
        const int l = row & (L_SEQ - 1);
        float acc[8];
#pragma unroll
        for (int ci = 0; ci < 8; ++ci) acc[ci] = cb[ci];
#pragma unroll
        for (int h = 0; h < 4; ++h) {
            const int lsrc = l - 3 + h;
            if (lsrc >= 0) {
                float4 a = *(const float4*)&x_in[(size_t)(row - 3 + h) * DINNER + c8];
                float4 b = *(const float4*)&x_in[(size_t)(row - 3 + h) * DINNER + c8 + 4];
                acc[0] += a.x * wt[0][h]; acc[1] += a.y * wt[1][h];
                acc[2] += a.z * wt[2][h]; acc[3] += a.w * wt[3][h];
                acc[4] += b.x * wt[4][h]; acc[5] += b.y * wt[5][h];
                acc[6] += b.z * wt[6][h]; acc[7] += b.w * wt[7][h];
            }
        }
        float o[8];
        ushort8v ob;
#pragma unroll
        for (int ci = 0; ci < 8; ++ci) {
            o[ci] = silu_f(acc[ci]);
            sxc[rr][c8 + ci] = o[ci];
            ob[ci] = (short)f2bf(o[ci]);
        }
        *(ushort8v*)&x_conv_bf[(size_t)row * DINNER + c8] = ob;
    }
    __syncthreads();

    const int n = tid & 31;
    const int g = tid >> 5;
    float p[CROWS] = {};
    const int k0 = g * 256;
#pragma unroll 4
    for (int k = k0; k < k0 + 256; ++k) {
        const float wv = W_xp[k * 32 + n];
        p[0] += sxc[0][k] * wv;
        p[1] += sxc[1][k] * wv;
        p[2] += sxc[2][k] * wv;
        p[3] += sxc[3][k] * wv;
    }
#pragma unroll
    for (int rr = 0; rr < CROWS; ++rr) red[g][rr][n] = p[rr];
    __syncthreads();
    if (tid < CROWS * 32) {
        const int rr = tid >> 5;
        const int n2 = tid & 31;
        float s = b_xp[n2];
#pragma unroll
        for (int gg = 0; gg < 8; ++gg) s += red[gg][rr][n2];
        BC[(size_t)(r0 + rr) * 32 + n2] = s;
    }
}

// ---------------------------------------------------------------------------
// Chunked two-pass selective scan (round-6 proven: DT=16/CCH=64, 37 KB LDS,
// conflict-free combine, all sequential inputs coalesced bf16x8 [D][B*L]).
// ---------------------------------------------------------------------------
__global__ __launch_bounds__(1024, 4) void scan_kernel(
    const unsigned short* __restrict__ deltaT,
    const unsigned short* __restrict__ xcT,
    const float* __restrict__ BC, const float* __restrict__ A_log,
    const float* __restrict__ D_skip, const unsigned short* __restrict__ zt,
    unsigned short* __restrict__ y_bf)
{
    __shared__ unsigned short sH[DSTATE * SSTR];   // 33.3 KB
    __shared__ float sDsum[CCH * DT];              // 4 KB

    const int tid = threadIdx.x;
    const int dl  = tid & (DT - 1);
    const int c   = tid >> 4;
    const int b   = blockIdx.x >> 7;
    const int d0  = (blockIdx.x & 127) * DT;
    const int d   = d0 + dl;

    const int l0 = c * CS;
    const int row0 = b * L_SEQ + l0;

    const unsigned short* dpt = deltaT + (size_t)d * (B_SZ * L_SEQ) + row0;
    bf16x8 dv0 = *(const bf16x8*)dpt;
    bf16x8 dv1 = *(const bf16x8*)(dpt + 8);
    const unsigned short* xpt = xcT + (size_t)d * (B_SZ * L_SEQ) + row0;
    bf16x8 xv0 = *(const bf16x8*)xpt;
    bf16x8 xv1 = *(const bf16x8*)(xpt + 8);
    const unsigned short* gpt = zt + (size_t)d * (B_SZ * L_SEQ) + row0;
    bf16x8 gv0 = *(const bf16x8*)gpt;
    bf16x8 gv1 = *(const bf16x8*)(gpt + 8);

    float Al[DSTATE];
#pragma unroll
    for (int s = 0; s < DSTATE; ++s)
        Al[s] = -__expf(A_log[d * DSTATE + s]) * 1.44269504f;
    const float Dsk = D_skip[d];

    float dts[CS], xcs[CS];
    float dsum = 0.f;
#pragma unroll
    for (int k = 0; k < 8; ++k) {
        dts[k]     = bf2f((unsigned short)dv0[k]);
        dts[8 + k] = bf2f((unsigned short)dv1[k]);
        xcs[k]     = bf2f((unsigned short)xv0[k]);
        xcs[8 + k] = bf2f((unsigned short)xv1[k]);
    }
#pragma unroll
    for (int k = 0; k < CS; ++k) dsum += dts[k];

    float h[DSTATE];
#pragma unroll
    for (int s = 0; s < DSTATE; ++s) h[s] = 0.f;

    const float* bcp = BC + (size_t)row0 * 32;

    // ---- pass 1: chunk summaries from h=0 ----
#pragma unroll 4
    for (int j = 0; j < CS; ++j) {
        const float dt = dts[j];
        const float xc = xcs[j];
        float Bv[DSTATE];
        *(float4*)&Bv[0]  = *(const float4*)(bcp + j * 32 + 0);
        *(float4*)&Bv[4]  = *(const float4*)(bcp + j * 32 + 4);
        *(float4*)&Bv[8]  = *(const float4*)(bcp + j * 32 + 8);
        *(float4*)&Bv[12] = *(const float4*)(bcp + j * 32 + 12);
        const float dlx = dt * xc;
#pragma unroll
        for (int s = 0; s < DSTATE; ++s) {
            const float e = nexp2(dt * Al[s]);
            h[s] = e * h[s] + dlx * Bv[s];
        }
    }
#pragma unroll
    for (int s = 0; s < DSTATE; ++s)
        sH[s * SSTR + tid] = f2bf(h[s]);
    sDsum[tid] = dsum;
    __syncthreads();

    // ---- combine: sequential over chunks, parallel over (s, dl) ----
    if (tid < DSTATE * DT) {
        const int dl2 = tid & (DT - 1);
        const int s2  = tid >> 4;
        const float Alc = -__expf(A_log[(d0 + dl2) * DSTATE + s2]) * 1.44269504f;
        float hh = 0.f;
        for (int c2 = 0; c2 < CCH; ++c2) {
            const int idx = s2 * SSTR + c2 * DT + dl2;
            const float a  = nexp2(Alc * sDsum[c2 * DT + dl2]);
            const float he = bf2f(sH[idx]);
            sH[idx] = f2bf(hh);
            hh = a * hh + he;
        }
    }
    __syncthreads();

#pragma unroll
    for (int s = 0; s < DSTATE; ++s) h[s] = bf2f(sH[s * SSTR + tid]);

    // ---- pass 2: rescan with true h0, fuse D_skip + precomputed gate ----
    unsigned short* yp = y_bf + (size_t)row0 * DINNER + d;
#pragma unroll
    for (int j = 0; j < 8; ++j) {
        const float dt = dts[j];
        const float xc = xcs[j];
        const float g  = bf2f((unsigned short)gv0[j]);
        float Bv[DSTATE], Cv[DSTATE];
        *(float4*)&Bv[0]  = *(const float4*)(bcp + j * 32 + 0);
        *(float4*)&Bv[4]  = *(const float4*)(bcp + j * 32 + 4);
        *(float4*)&Bv[8]  = *(const float4*)(bcp + j * 32 + 8);
        *(float4*)&Bv[12] = *(const float4*)(bcp + j * 32 + 12);
        *(float4*)&Cv[0]  = *(const float4*)(bcp + j * 32 + 16);
        *(float4*)&Cv[4]  = *(const float4*)(bcp + j * 32 + 20);
        *(float4*)&Cv[8]  = *(const float4*)(bcp + j * 32 + 24);
        *(float4*)&Cv[12] = *(const float4*)(bcp + j * 32 + 28);
        const float dlx = dt * xc;
        float y = Dsk * xc;
#pragma unroll
        for (int s = 0; s < DSTATE; ++s) {
            const float e = nexp2(dt * Al[s]);
            h[s] = e * h[s] + dlx * Bv[s];
            y += h[s] * Cv[s];
        }
        yp[j * DINNER] = f2bf(y * g);
    }
#pragma unroll
    for (int j2 = 0; j2 < 8; ++j2) {
        const int j = j2 + 8;
        const float dt = dts[j];
        const float xc = xcs[j];
        const float g  = bf2f((unsigned short)gv1[j2]);
        float Bv[DSTATE], Cv[DSTATE];
        *(float4*)&Bv[0]  = *(const float4*)(bcp + j * 32 + 0);
        *(float4*)&Bv[4]  = *(const float4*)(bcp + j * 32 + 4);
        *(float4*)&Bv[8]  = *(const float4*)(bcp + j * 32 + 8);
        *(float4*)&Bv[12] = *(const float4*)(bcp + j * 32 + 12);
        *(float4*)&Cv[0]  = *(const float4*)(bcp + j * 32 + 16);
        *(float4*)&Cv[4]  = *(const float4*)(bcp + j * 32 + 20);
        *(float4*)&Cv[8]  = *(const float4*)(bcp + j * 32 + 24);
        *(float4*)&Cv[12] = *(const float4*)(bcp + j * 32 + 28);
        const float dlx = dt * xc;
        float y = Dsk * xc;
#pragma unroll
        for (int s = 0; s < DSTATE; ++s) {
            const float e = nexp2(dt * Al[s]);
            h[s] = e * h[s] + dlx * Bv[s];
            y += h[s] * Cv[s];
        }
        yp[j * DINNER] = f2bf(y * g);
    }
}

// ---------------------------------------------------------------------------
// Row LayerNorm: unbiased variance (N-1), eps added to std.
// ---------------------------------------------------------------------------
__global__ __launch_bounds__(256) void layernorm_kernel(
    const float* __restrict__ t, const float* __restrict__ alpha,
    const float* __restrict__ beta, float* __restrict__ out)
{
    __shared__ float sred[4];
    __shared__ float sred2[4];
    const int row = blockIdx.x;
    const int tid = threadIdx.x;
    const float* r = t + (size_t)row * DMODEL;

    float4 v = *(const float4*)&r[tid * 4];
    float lsum = v.x + v.y + v.z + v.w;
#pragma unroll
    for (int m = 1; m < 64; m <<= 1) lsum += __shfl_xor(lsum, m);
    if ((tid & 63) == 0) sred[tid >> 6] = lsum;
    __syncthreads();
    const float mean = (sred[0] + sred[1] + sred[2] + sred[3]) * (1.f / DMODEL);

    const float dx = v.x - mean, dy = v.y - mean, dz = v.z - mean, dw = v.w - mean;
    float ls2 = dx * dx + dy * dy + dz * dz + dw * dw;
#pragma unroll
    for (int m = 1; m < 64; m <<= 1) ls2 += __shfl_xor(ls2, m);
    if ((tid & 63) == 0) sred2[tid >> 6] = ls2;
    __syncthreads();
    const float var = (sred2[0] + sred2[1] + sred2[2] + sred2[3]) * (1.f / (DMODEL - 1));
    const float inv = 1.f / (sqrtf(var) + EPSV);

    float4 a4 = *(const float4*)&alpha[tid * 4];
    float4 b4 = *(const float4*)&beta[tid * 4];
    float4 o;
    o.x = a4.x * dx * inv + b4.x;
    o.y = a4.y * dy * inv + b4.y;
    o.z = a4.z * dz * inv + b4.z;
    o.w = a4.w * dw * inv + b4.w;
    *(float4*)&out[(size_t)row * DMODEL + tid * 4] = o;
}

// ---------------------------------------------------------------------------
extern "C" void kernel_launch(void* const* d_in, const int* in_sizes, int n_in,
                              void* d_out, int out_size, void* d_ws, size_t ws_size,
                              hipStream_t stream)
{
    const float* x      = (const float*)d_in[0];
    const float* W_in   = (const float*)d_in[1];
    const float* b_in   = (const float*)d_in[2];
    const float* conv_w = (const float*)d_in[3];
    const float* conv_b = (const float*)d_in[4];
    const float* W_xp   = (const float*)d_in[5];
    const float* b_xp   = (const float*)d_in[6];
    const float* W_dt   = (const float*)d_in[7];
    const float* b_dt   = (const float*)d_in[8];
    const float* A_log  = (const float*)d_in[9];
    const float* D_skip = (const float*)d_in[10];
    const float* W_out  = (const float*)d_in[11];
    const float* b_out  = (const float*)d_in[12];
    const float* alpha  = (const float*)d_in[13];
    const float* beta   = (const float*)d_in[14];
    float* out = (float*)d_out;

    const size_t M = (size_t)B_SZ * L_SEQ;  // 2048 rows
    char* ws = (char*)d_ws;
    float* x_in    = (float*)(ws + 0);                  // 16 MB (reused as tpre)
    unsigned short* zt = (unsigned short*)(ws + (16u << 20));      // 8 MB, [D][B*L]
    unsigned short* deltaT = (unsigned short*)(ws + (48u << 20));  // 8 MB, [D][B*L]
    float* BC      = (float*)(ws + (64u << 20));        // 0.5 MB
    unsigned short* W_in_t     = (unsigned short*)(ws + (69u << 20));  // 8 MB
    unsigned short* W_dt_t     = (unsigned short*)(ws + (77u << 20));  // 8 MB
    unsigned short* W_out_t    = (unsigned short*)(ws + (85u << 20));  // 4 MB
    unsigned short* x_conv_bf  = (unsigned short*)(ws + (89u << 20));  // 8 MB
    unsigned short* xcT        = (unsigned short*)(ws + (24u << 20));  // 8 MB, [D][B*L]
    unsigned short* ygate_bf   = (unsigned short*)(ws + (77u << 20));  // reuse W_dt_t
    float* tpre = x_in;

    const dim3 blk(256);

    // 0. prep: weight transposes only (x cast folded into gemm1)
    prep_kernel<<<dim3(10240), blk, 0, stream>>>(
        W_in, W_in_t, W_dt, W_dt_t, W_out, W_out_t);

    // 1. xz = x @ W_in + b_in (2048 x 4096 x 1024), A = x f32 (inline cast).
    //    MODE 5: x_in half -> f32 [M][2048]; z half -> silu -> bf16 zt[D][M]
    gemm_bf16<128, 128, 5, 2, true, 0><<<dim3(4096 / 128, 2048 / 128), blk, 0, stream>>>(
        (const void*)x, W_in_t, b_in, nullptr, x_in, zt, nullptr, nullptr,
        2048, 4096, 1024);

    // 2+3. conv + SiLU + x_proj (fused)
    conv_xproj<<<dim3((unsigned)(M / CROWS)), blk, 0, stream>>>(
        x_in, conv_w, conv_b, W_xp, b_xp, x_conv_bf, BC);

    // 4. deltaT = softplus(x_conv @ W_dt + b_dt)^T -> bf16 [D][B*L]
    //    + 1024 extra blocks do x_conv [M][D] -> xcT [D][M] (old transp kernel)
    gemm_bf16<128, 64, 4, 3, false, 512><<<dim3(512 + 1024), blk, 0, stream>>>(
        x_conv_bf, W_dt_t, b_dt, nullptr, (float*)deltaT, nullptr,
        x_conv_bf, xcT, 2048, 2048, 2048);

    // 5. chunked two-pass selective scan + D_skip + gate -> bf16
    scan_kernel<<<dim3(B_SZ * (DINNER / DT)), dim3(1024), 0, stream>>>(
        deltaT, xcT, BC, A_log, D_skip, zt, ygate_bf);

    // 6. tpre = ygate @ W_out + b_out + x  (2048 x 1024 x 2048), 64x64 (r4 best)
    gemm_bf16<64, 64, 2, 3, false, 0><<<dim3(1024 / 64, 2048 / 64), blk, 0, stream>>>(
        ygate_bf, W_out_t, b_out, x, tpre, nullptr, nullptr, nullptr,
        2048, 1024, 2048);

    // 7. LayerNorm
    layernorm_kernel<<<dim3((unsigned)M), blk, 0, stream>>>(tpre, alpha, beta, out);
}

// Round 10
// 269.621 us; speedup vs baseline: 1.0688x; 1.0688x over previous
//
#include <hip/hip_runtime.h>
#include <math.h>

#define B_SZ    2
#define L_SEQ   1024
#define DMODEL  1024
#define DINNER  2048
#define DSTATE  16
#define EPSV    1e-6f

// scan decomposition: 16 channels/block, 64 chunks of 16 steps, 1024 thr/block
#define CCH 64
#define CS  (L_SEQ / CCH)      // 16
#define DT  16
#define SSTR 1040              // CCH*DT + 16 (520 dwords == 8 mod 32, conflict-free combine)

typedef short  bf16x8  __attribute__((ext_vector_type(8)));
typedef float  floatx4 __attribute__((ext_vector_type(4)));
typedef unsigned short ushort8v __attribute__((ext_vector_type(8)));

extern "C" __device__ float __ocml_native_exp2_f32(float);
extern "C" __device__ float __ocml_native_log2_f32(float);

__device__ __forceinline__ float nexp2(float x) { return __ocml_native_exp2_f32(x); }

__device__ __forceinline__ float softplus_f(float v) {
    if (v > 20.f) return v;
    return 0.69314718f * __ocml_native_log2_f32(1.f + nexp2(v * 1.44269504f));
}
__device__ __forceinline__ float silu_f(float z) {
    return z / (1.f + nexp2(z * -1.44269504f));
}

__device__ __forceinline__ unsigned short f2bf(float f) {
    unsigned int u = __float_as_uint(f);
    unsigned int r = (u + 0x7FFFu + ((u >> 16) & 1u)) >> 16;
    return (unsigned short)r;
}
__device__ __forceinline__ float bf2f(unsigned short u) {
    return __uint_as_float(((unsigned int)u) << 16);
}

// async global->LDS, 16 B per lane. LDS dest = wave-uniform base + lane*16.
__device__ __forceinline__ void gload_lds16(const unsigned short* g, unsigned short* l) {
    __builtin_amdgcn_global_load_lds(
        (const __attribute__((address_space(1))) unsigned int*)g,
        (__attribute__((address_space(3))) unsigned int*)l,
        16, 0, 0);
}

// ---------------------------------------------------------------------------
// Fused prep: 3 weight transposes (+cast) and the x cast, one launch.
// ---------------------------------------------------------------------------
__global__ __launch_bounds__(256) void prep_kernel(
    const float* __restrict__ x, unsigned short* __restrict__ x_bf,
    const float* __restrict__ W_in, unsigned short* __restrict__ W_in_t,
    const float* __restrict__ W_dt, unsigned short* __restrict__ W_dt_t,
    const float* __restrict__ W_out, unsigned short* __restrict__ W_out_t)
{
    const int bid = blockIdx.x;
    if (bid >= 10240) {
        const int i = (bid - 10240) * 256 + threadIdx.x;
        float4 v = ((const float4*)x)[i];
        ushort4 o = { f2bf(v.x), f2bf(v.y), f2bf(v.z), f2bf(v.w) };
        ((ushort4*)x_bf)[i] = o;
        return;
    }
    __shared__ float tile[32][33];
    const float* W; unsigned short* Wt; int K, N, t;
    if (bid < 4096)      { W = W_in;  Wt = W_in_t;  K = 1024; N = 4096; t = bid; }
    else if (bid < 8192) { W = W_dt;  Wt = W_dt_t;  K = 2048; N = 2048; t = bid - 4096; }
    else                 { W = W_out; Wt = W_out_t; K = 2048; N = 1024; t = bid - 8192; }
    const int nx = N >> 5;
    const int n0 = (t % nx) * 32;
    const int k0 = (t / nx) * 32;
    const int c = threadIdx.x & 31;
    const int r = threadIdx.x >> 5;
#pragma unroll
    for (int i = 0; i < 4; ++i)
        tile[r + 8 * i][c] = W[(size_t)(k0 + r + 8 * i) * N + n0 + c];
    __syncthreads();
#pragma unroll
    for (int i = 0; i < 4; ++i)
        Wt[(size_t)(n0 + r + 8 * i) * K + k0 + c] = f2bf(tile[c][r + 8 * i]);
}

// ---------------------------------------------------------------------------
// bf16 [M][D] -> [D][M] transpose via 64x66 LDS tile.
// ---------------------------------------------------------------------------
__global__ __launch_bounds__(256) void transp_bf16(
    const unsigned short* __restrict__ in, unsigned short* __restrict__ outp)
{
    __shared__ unsigned short tile[64][66];
    const int bx = blockIdx.x & 31;    // M tile index (2048/64)
    const int by = blockIdx.x >> 5;    // D tile index (2048/64)
    const int m0 = bx * 64, d0 = by * 64;
    const int tid = threadIdx.x;
    const int r = tid >> 3;            // 0..31
    const int c = (tid & 7) * 8;       // 0..56
#pragma unroll
    for (int i = 0; i < 2; ++i) {
        const int row = r + i * 32;
        ushort8v v = *(const ushort8v*)&in[(size_t)(m0 + row) * DINNER + d0 + c];
        *(ushort8v*)&tile[row][c] = v;
    }
    __syncthreads();
#pragma unroll
    for (int i = 0; i < 2; ++i) {
        const int dd = r + i * 32;
        ushort8v o;
#pragma unroll
        for (int k = 0; k < 8; ++k) o[k] = tile[c + k][dd];
        *(ushort8v*)&outp[(size_t)(d0 + dd) * (B_SZ * L_SEQ) + m0 + c] = o;
    }
}

// ---------------------------------------------------------------------------
// bf16 MFMA GEMM — global_load_lds width-16 staging, swizzle folded into the
// per-lane global address (LDS linear, image identical to reg-staged layout).
// 2x2 waves, wave tile (TM/2)x(TN/2). Round-10: smaller tiles -> more
// blocks/CU (r9 counters: 128x128 grid=512 capped occupancy at 18.8%,
// MfmaUtil 11% -- barrier drain with only 2 blocks/CU is the GEMM limiter).
// MODE 0: +bias; 1: softplus(+bias); 2: +bias+resid;
// 4: softplus(+bias) -> bf16 transposed Ct[col][row];
// 5: split: cols<DINNER -> f32 C; cols>=DINNER -> silu -> bf16 zout^T.
// ---------------------------------------------------------------------------
template <int TM, int TN, int MODE, int MINW>
__global__ __launch_bounds__(256, MINW) void gemm_bf16(
    const unsigned short* __restrict__ A, const unsigned short* __restrict__ Bt,
    const float* __restrict__ bias, const float* __restrict__ resid,
    float* __restrict__ C, unsigned short* __restrict__ zout,
    int M, int N, int K)
{
    constexpr int MI = TM / 32;
    constexpr int NJ = TN / 32;
    constexpr int NINSTR = (TM + TN) / 8;   // 8 rows (1 KB) per instr
    constexpr int NI = NINSTR / 4;          // instrs per wave

    __shared__ unsigned short As[TM * 64];
    __shared__ unsigned short Bs[TN * 64];

    const int tid  = threadIdx.x;
    const int wave = tid >> 6;
    const int lane = tid & 63;
    const int m0 = blockIdx.y * TM;
    const int n0 = blockIdx.x * TN;
    const int wm = (wave >> 1) * (TM / 2);
    const int wn = (wave & 1) * (TN / 2);
    const int fr = lane & 15;
    const int kg = lane >> 4;

    // per-wave staging descriptors: global src per-lane (swizzled), LDS base uniform
    const unsigned short* gq[NI];
    unsigned short* lq[NI];
#pragma unroll
    for (int q = 0; q < NI; ++q) {
        const int idx = wave * NI + q;
        const int r0i = idx * 8;
        const int sub = lane >> 3;
        const int pos = lane & 7;
        if (r0i < TM) {
            const int row = r0i + sub;
            const int ch  = pos ^ (row & 7);
            gq[q] = A + (size_t)(m0 + row) * K + ch * 8;
            lq[q] = &As[r0i * 64];
        } else {
            const int rb = r0i - TM + sub;
            const int ch = pos ^ (rb & 7);
            gq[q] = Bt + (size_t)(n0 + rb) * K + ch * 8;
            lq[q] = &Bs[(r0i - TM) * 64];
        }
    }

    floatx4 acc[MI][NJ] = {};

#pragma unroll
    for (int q = 0; q < NI; ++q) gload_lds16(gq[q], lq[q]);

    for (int kt = 0; kt < K; kt += 64) {
        __syncthreads();   // vmcnt drained before barrier -> staging visible

#pragma unroll
        for (int ks = 0; ks < 2; ++ks) {
            const int cq = (ks << 2) | kg;
            bf16x8 af[MI], bfv[NJ];
#pragma unroll
            for (int i = 0; i < MI; ++i) {
                const int row = wm + i * 16 + fr;
                af[i] = *(const bf16x8*)&As[row * 64 + ((cq ^ (row & 7)) << 3)];
            }
#pragma unroll
            for (int j = 0; j < NJ; ++j) {
                const int row = wn + j * 16 + fr;
                bfv[j] = *(const bf16x8*)&Bs[row * 64 + ((cq ^ (row & 7)) << 3)];
            }
#pragma unroll
            for (int i = 0; i < MI; ++i)
#pragma unroll
                for (int j = 0; j < NJ; ++j)
                    acc[i][j] = __builtin_amdgcn_mfma_f32_16x16x32_bf16(
                        af[i], bfv[j], acc[i][j], 0, 0, 0);
        }

        if (kt + 64 < K) {
            __syncthreads();   // all reads done before overwrite
#pragma unroll
            for (int q = 0; q < NI; ++q) gload_lds16(gq[q] + kt + 64, lq[q]);
        }
    }

    const int rq = (lane >> 4) * 4;
    if (MODE == 4) {
        unsigned short* Ct = (unsigned short*)C;
#pragma unroll
        for (int i = 0; i < MI; ++i) {
#pragma unroll
            for (int j = 0; j < NJ; ++j) {
                const int col = n0 + wn + j * 16 + fr;
                const float bv = bias[col];
                const int row0 = m0 + wm + i * 16 + rq;
                ushort4 o;
#pragma unroll
                for (int r = 0; r < 4; ++r)
                    (&o.x)[r] = f2bf(softplus_f(acc[i][j][r] + bv));
                *(ushort4*)&Ct[(size_t)col * M + row0] = o;
            }
        }
    } else if (MODE == 5) {
        if (n0 < DINNER) {
#pragma unroll
            for (int i = 0; i < MI; ++i) {
#pragma unroll
                for (int j = 0; j < NJ; ++j) {
                    const int col = n0 + wn + j * 16 + fr;
                    const float bv = bias[col];
#pragma unroll
                    for (int r = 0; r < 4; ++r) {
                        const int row = m0 + wm + i * 16 + rq + r;
                        C[(size_t)row * DINNER + col] = acc[i][j][r] + bv;
                    }
                }
            }
        } else {
#pragma unroll
            for (int i = 0; i < MI; ++i) {
#pragma unroll
                for (int j = 0; j < NJ; ++j) {
                    const int col = n0 + wn + j * 16 + fr;
                    const float bv = bias[col];
                    const int row0 = m0 + wm + i * 16 + rq;
                    ushort4 o;
#pragma unroll
                    for (int r = 0; r < 4; ++r)
                        (&o.x)[r] = f2bf(silu_f(acc[i][j][r] + bv));
                    *(ushort4*)&zout[(size_t)(col - DINNER) * M + row0] = o;
                }
            }
        }
    } else {
#pragma unroll
        for (int i = 0; i < MI; ++i) {
#pragma unroll
            for (int j = 0; j < NJ; ++j) {
                const int col = n0 + wn + j * 16 + fr;
                const float bv = bias[col];
#pragma unroll
                for (int r = 0; r < 4; ++r) {
                    const int row = m0 + wm + i * 16 + rq + r;
                    float v = acc[i][j][r] + bv;
                    if (MODE == 1) {
                        v = softplus_f(v);
                    } else if (MODE == 2) {
                        v += resid[(size_t)row * N + col];
                    }
                    C[(size_t)row * N + col] = v;
                }
            }
        }
    }
}

// ---------------------------------------------------------------------------
// Fused depthwise causal conv1d(k=4) + SiLU + x_proj. bf16 x_conv only.
// ---------------------------------------------------------------------------
#define CROWS 4
__global__ __launch_bounds__(256) void conv_xproj(
    const float* __restrict__ x_in, const float* __restrict__ conv_w,
    const float* __restrict__ conv_b, const float* __restrict__ W_xp,
    const float* __restrict__ b_xp,
    unsigned short* __restrict__ x_conv_bf, float* __restrict__ BC)
{
    __shared__ float sxc[CROWS][DINNER];   // 32 KB
    __shared__ float red[8][CROWS][32];    // 4 KB

    const int tid = threadIdx.x;
    const int r0 = blockIdx.x * CROWS;
    const int c8 = tid * 8;

    float wt[8][4];
#pragma unroll
    for (int ci = 0; ci < 8; ++ci) {
        float4 w4 = *(const float4*)&conv_w[(c8 + ci) * 4];
        wt[ci][0] = w4.x; wt[ci][1] = w4.y; wt[ci][2] = w4.z; wt[ci][3] = w4.w;
    }
    float cb[8];
    *(float4*)&cb[0] = *(const float4*)&conv_b[c8];
    *(float4*)&cb[4] = *(const float4*)&conv_b[c8 + 4];

#pragma unroll
    for (int rr = 0; rr < CROWS; ++rr) {
        const int row = r0 + rr;
        const int l = row & (L_SEQ - 1);
        float acc[8];
#pragma unroll
        for (int ci = 0; ci < 8; ++ci) acc[ci] = cb[ci];
#pragma unroll
        for (int h = 0; h < 4; ++h) {
            const int lsrc = l - 3 + h;
            if (lsrc >= 0) {
                float4 a = *(const float4*)&x_in[(size_t)(row - 3 + h) * DINNER + c8];
                float4 b = *(const float4*)&x_in[(size_t)(row - 3 + h) * DINNER + c8 + 4];
                acc[0] += a.x * wt[0][h]; acc[1] += a.y * wt[1][h];
                acc[2] += a.z * wt[2][h]; acc[3] += a.w * wt[3][h];
                acc[4] += b.x * wt[4][h]; acc[5] += b.y * wt[5][h];
                acc[6] += b.z * wt[6][h]; acc[7] += b.w * wt[7][h];
            }
        }
        float o[8];
        ushort8v ob;
#pragma unroll
        for (int ci = 0; ci < 8; ++ci) {
            o[ci] = silu_f(acc[ci]);
            sxc[rr][c8 + ci] = o[ci];
            ob[ci] = (short)f2bf(o[ci]);
        }
        *(ushort8v*)&x_conv_bf[(size_t)row * DINNER + c8] = ob;
    }
    __syncthreads();

    const int n = tid & 31;
    const int g = tid >> 5;
    float p[CROWS] = {};
    const int k0 = g * 256;
#pragma unroll 4
    for (int k = k0; k < k0 + 256; ++k) {
        const float wv = W_xp[k * 32 + n];
        p[0] += sxc[0][k] * wv;
        p[1] += sxc[1][k] * wv;
        p[2] += sxc[2][k] * wv;
        p[3] += sxc[3][k] * wv;
    }
#pragma unroll
    for (int rr = 0; rr < CROWS; ++rr) red[g][rr][n] = p[rr];
    __syncthreads();
    if (tid < CROWS * 32) {
        const int rr = tid >> 5;
        const int n2 = tid & 31;
        float s = b_xp[n2];
#pragma unroll
        for (int gg = 0; gg < 8; ++gg) s += red[gg][rr][n2];
        BC[(size_t)(r0 + rr) * 32 + n2] = s;
    }
}

// ---------------------------------------------------------------------------
// Chunked two-pass selective scan (round-6 proven: DT=16/CCH=64, 37 KB LDS,
// conflict-free combine, all sequential inputs coalesced bf16x8 [D][B*L]).
// ---------------------------------------------------------------------------
__global__ __launch_bounds__(1024, 4) void scan_kernel(
    const unsigned short* __restrict__ deltaT,
    const unsigned short* __restrict__ xcT,
    const float* __restrict__ BC, const float* __restrict__ A_log,
    const float* __restrict__ D_skip, const unsigned short* __restrict__ zt,
    unsigned short* __restrict__ y_bf)
{
    __shared__ unsigned short sH[DSTATE * SSTR];   // 33.3 KB
    __shared__ float sDsum[CCH * DT];              // 4 KB

    const int tid = threadIdx.x;
    const int dl  = tid & (DT - 1);
    const int c   = tid >> 4;
    const int b   = blockIdx.x >> 7;
    const int d0  = (blockIdx.x & 127) * DT;
    const int d   = d0 + dl;

    const int l0 = c * CS;
    const int row0 = b * L_SEQ + l0;

    const unsigned short* dpt = deltaT + (size_t)d * (B_SZ * L_SEQ) + row0;
    bf16x8 dv0 = *(const bf16x8*)dpt;
    bf16x8 dv1 = *(const bf16x8*)(dpt + 8);
    const unsigned short* xpt = xcT + (size_t)d * (B_SZ * L_SEQ) + row0;
    bf16x8 xv0 = *(const bf16x8*)xpt;
    bf16x8 xv1 = *(const bf16x8*)(xpt + 8);
    const unsigned short* gpt = zt + (size_t)d * (B_SZ * L_SEQ) + row0;
    bf16x8 gv0 = *(const bf16x8*)gpt;
    bf16x8 gv1 = *(const bf16x8*)(gpt + 8);

    float Al[DSTATE];
#pragma unroll
    for (int s = 0; s < DSTATE; ++s)
        Al[s] = -__expf(A_log[d * DSTATE + s]) * 1.44269504f;
    const float Dsk = D_skip[d];

    float dts[CS], xcs[CS];
    float dsum = 0.f;
#pragma unroll
    for (int k = 0; k < 8; ++k) {
        dts[k]     = bf2f((unsigned short)dv0[k]);
        dts[8 + k] = bf2f((unsigned short)dv1[k]);
        xcs[k]     = bf2f((unsigned short)xv0[k]);
        xcs[8 + k] = bf2f((unsigned short)xv1[k]);
    }
#pragma unroll
    for (int k = 0; k < CS; ++k) dsum += dts[k];

    float h[DSTATE];
#pragma unroll
    for (int s = 0; s < DSTATE; ++s) h[s] = 0.f;

    const float* bcp = BC + (size_t)row0 * 32;

    // ---- pass 1: chunk summaries from h=0 ----
#pragma unroll 4
    for (int j = 0; j < CS; ++j) {
        const float dt = dts[j];
        const float xc = xcs[j];
        float Bv[DSTATE];
        *(float4*)&Bv[0]  = *(const float4*)(bcp + j * 32 + 0);
        *(float4*)&Bv[4]  = *(const float4*)(bcp + j * 32 + 4);
        *(float4*)&Bv[8]  = *(const float4*)(bcp + j * 32 + 8);
        *(float4*)&Bv[12] = *(const float4*)(bcp + j * 32 + 12);
        const float dlx = dt * xc;
#pragma unroll
        for (int s = 0; s < DSTATE; ++s) {
            const float e = nexp2(dt * Al[s]);
            h[s] = e * h[s] + dlx * Bv[s];
        }
    }
#pragma unroll
    for (int s = 0; s < DSTATE; ++s)
        sH[s * SSTR + tid] = f2bf(h[s]);
    sDsum[tid] = dsum;
    __syncthreads();

    // ---- combine: sequential over chunks, parallel over (s, dl) ----
    if (tid < DSTATE * DT) {
        const int dl2 = tid & (DT - 1);
        const int s2  = tid >> 4;
        const float Alc = -__expf(A_log[(d0 + dl2) * DSTATE + s2]) * 1.44269504f;
        float hh = 0.f;
        for (int c2 = 0; c2 < CCH; ++c2) {
            const int idx = s2 * SSTR + c2 * DT + dl2;
            const float a  = nexp2(Alc * sDsum[c2 * DT + dl2]);
            const float he = bf2f(sH[idx]);
            sH[idx] = f2bf(hh);
            hh = a * hh + he;
        }
    }
    __syncthreads();

#pragma unroll
    for (int s = 0; s < DSTATE; ++s) h[s] = bf2f(sH[s * SSTR + tid]);

    // ---- pass 2: rescan with true h0, fuse D_skip + precomputed gate ----
    unsigned short* yp = y_bf + (size_t)row0 * DINNER + d;
#pragma unroll
    for (int j = 0; j < 8; ++j) {
        const float dt = dts[j];
        const float xc = xcs[j];
        const float g  = bf2f((unsigned short)gv0[j]);
        float Bv[DSTATE], Cv[DSTATE];
        *(float4*)&Bv[0]  = *(const float4*)(bcp + j * 32 + 0);
        *(float4*)&Bv[4]  = *(const float4*)(bcp + j * 32 + 4);
        *(float4*)&Bv[8]  = *(const float4*)(bcp + j * 32 + 8);
        *(float4*)&Bv[12] = *(const float4*)(bcp + j * 32 + 12);
        *(float4*)&Cv[0]  = *(const float4*)(bcp + j * 32 + 16);
        *(float4*)&Cv[4]  = *(const float4*)(bcp + j * 32 + 20);
        *(float4*)&Cv[8]  = *(const float4*)(bcp + j * 32 + 24);
        *(float4*)&Cv[12] = *(const float4*)(bcp + j * 32 + 28);
        const float dlx = dt * xc;
        float y = Dsk * xc;
#pragma unroll
        for (int s = 0; s < DSTATE; ++s) {
            const float e = nexp2(dt * Al[s]);
            h[s] = e * h[s] + dlx * Bv[s];
            y += h[s] * Cv[s];
        }
        yp[j * DINNER] = f2bf(y * g);
    }
#pragma unroll
    for (int j2 = 0; j2 < 8; ++j2) {
        const int j = j2 + 8;
        const float dt = dts[j];
        const float xc = xcs[j];
        const float g  = bf2f((unsigned short)gv1[j2]);
        float Bv[DSTATE], Cv[DSTATE];
        *(float4*)&Bv[0]  = *(const float4*)(bcp + j * 32 + 0);
        *(float4*)&Bv[4]  = *(const float4*)(bcp + j * 32 + 4);
        *(float4*)&Bv[8]  = *(const float4*)(bcp + j * 32 + 8);
        *(float4*)&Bv[12] = *(const float4*)(bcp + j * 32 + 12);
        *(float4*)&Cv[0]  = *(const float4*)(bcp + j * 32 + 16);
        *(float4*)&Cv[4]  = *(const float4*)(bcp + j * 32 + 20);
        *(float4*)&Cv[8]  = *(const float4*)(bcp + j * 32 + 24);
        *(float4*)&Cv[12] = *(const float4*)(bcp + j * 32 + 28);
        const float dlx = dt * xc;
        float y = Dsk * xc;
#pragma unroll
        for (int s = 0; s < DSTATE; ++s) {
            const float e = nexp2(dt * Al[s]);
            h[s] = e * h[s] + dlx * Bv[s];
            y += h[s] * Cv[s];
        }
        yp[j * DINNER] = f2bf(y * g);
    }
}

// ---------------------------------------------------------------------------
// Row LayerNorm: unbiased variance (N-1), eps added to std.
// ---------------------------------------------------------------------------
__global__ __launch_bounds__(256) void layernorm_kernel(
    const float* __restrict__ t, const float* __restrict__ alpha,
    const float* __restrict__ beta, float* __restrict__ out)
{
    __shared__ float sred[4];
    __shared__ float sred2[4];
    const int row = blockIdx.x;
    const int tid = threadIdx.x;
    const float* r = t + (size_t)row * DMODEL;

    float4 v = *(const float4*)&r[tid * 4];
    float lsum = v.x + v.y + v.z + v.w;
#pragma unroll
    for (int m = 1; m < 64; m <<= 1) lsum += __shfl_xor(lsum, m);
    if ((tid & 63) == 0) sred[tid >> 6] = lsum;
    __syncthreads();
    const float mean = (sred[0] + sred[1] + sred[2] + sred[3]) * (1.f / DMODEL);

    const float dx = v.x - mean, dy = v.y - mean, dz = v.z - mean, dw = v.w - mean;
    float ls2 = dx * dx + dy * dy + dz * dz + dw * dw;
#pragma unroll
    for (int m = 1; m < 64; m <<= 1) ls2 += __shfl_xor(ls2, m);
    if ((tid & 63) == 0) sred2[tid >> 6] = ls2;
    __syncthreads();
    const float var = (sred2[0] + sred2[1] + sred2[2] + sred2[3]) * (1.f / (DMODEL - 1));
    const float inv = 1.f / (sqrtf(var) + EPSV);

    float4 a4 = *(const float4*)&alpha[tid * 4];
    float4 b4 = *(const float4*)&beta[tid * 4];
    float4 o;
    o.x = a4.x * dx * inv + b4.x;
    o.y = a4.y * dy * inv + b4.y;
    o.z = a4.z * dz * inv + b4.z;
    o.w = a4.w * dw * inv + b4.w;
    *(float4*)&out[(size_t)row * DMODEL + tid * 4] = o;
}

// ---------------------------------------------------------------------------
extern "C" void kernel_launch(void* const* d_in, const int* in_sizes, int n_in,
                              void* d_out, int out_size, void* d_ws, size_t ws_size,
                              hipStream_t stream)
{
    const float* x      = (const float*)d_in[0];
    const float* W_in   = (const float*)d_in[1];
    const float* b_in   = (const float*)d_in[2];
    const float* conv_w = (const float*)d_in[3];
    const float* conv_b = (const float*)d_in[4];
    const float* W_xp   = (const float*)d_in[5];
    const float* b_xp   = (const float*)d_in[6];
    const float* W_dt   = (const float*)d_in[7];
    const float* b_dt   = (const float*)d_in[8];
    const float* A_log  = (const float*)d_in[9];
    const float* D_skip = (const float*)d_in[10];
    const float* W_out  = (const float*)d_in[11];
    const float* b_out  = (const float*)d_in[12];
    const float* alpha  = (const float*)d_in[13];
    const float* beta   = (const float*)d_in[14];
    float* out = (float*)d_out;

    const size_t M = (size_t)B_SZ * L_SEQ;  // 2048 rows
    char* ws = (char*)d_ws;
    float* x_in    = (float*)(ws + 0);                  // 16 MB (reused as tpre)
    unsigned short* zt = (unsigned short*)(ws + (16u << 20));      // 8 MB, [D][B*L]
    unsigned short* deltaT = (unsigned short*)(ws + (48u << 20));  // 8 MB, [D][B*L]
    float* BC      = (float*)(ws + (64u << 20));        // 0.5 MB
    unsigned short* x_bf       = (unsigned short*)(ws + (64u << 20) + (512u << 10)); // 4 MB
    unsigned short* W_in_t     = (unsigned short*)(ws + (69u << 20));  // 8 MB
    unsigned short* W_dt_t     = (unsigned short*)(ws + (77u << 20));  // 8 MB
    unsigned short* W_out_t    = (unsigned short*)(ws + (85u << 20));  // 4 MB
    unsigned short* x_conv_bf  = (unsigned short*)(ws + (89u << 20));  // 8 MB
    unsigned short* xcT        = (unsigned short*)(ws + (24u << 20));  // 8 MB, [D][B*L]
    unsigned short* ygate_bf   = (unsigned short*)(ws + (77u << 20));  // reuse W_dt_t
    float* tpre = x_in;

    const dim3 blk(256);

    // 0. fused prep: weight transposes + x cast
    prep_kernel<<<dim3(12288), blk, 0, stream>>>(
        x, x_bf, W_in, W_in_t, W_dt, W_dt_t, W_out, W_out_t);

    // 1. xz = x @ W_in + b_in (2048 x 4096 x 1024), 64x128 tiles -> 1024
    //    blocks, 4 blocks/CU. MODE 5: x_in f32 + z -> silu -> bf16 zt[D][M]
    gemm_bf16<64, 128, 5, 4><<<dim3(4096 / 128, 2048 / 64), blk, 0, stream>>>(
        x_bf, W_in_t, b_in, nullptr, x_in, zt, 2048, 4096, 1024);

    // 2+3. conv + SiLU + x_proj (fused)
    conv_xproj<<<dim3((unsigned)(M / CROWS)), blk, 0, stream>>>(
        x_in, conv_w, conv_b, W_xp, b_xp, x_conv_bf, BC);

    // 3b. x_conv [M][D] -> xcT [D][M] (coalesced bf16 path for scan)
    transp_bf16<<<dim3(1024), blk, 0, stream>>>(x_conv_bf, xcT);

    // 4. deltaT = softplus(x_conv @ W_dt + b_dt)^T -> bf16 [D][B*L],
    //    64x64 tiles -> 1024 blocks, 4 blocks/CU
    gemm_bf16<64, 64, 4, 4><<<dim3(2048 / 64, 2048 / 64), blk, 0, stream>>>(
        x_conv_bf, W_dt_t, b_dt, nullptr, (float*)deltaT, nullptr, 2048, 2048, 2048);

    // 5. chunked two-pass selective scan + D_skip + gate -> bf16
    scan_kernel<<<dim3(B_SZ * (DINNER / DT)), dim3(1024), 0, stream>>>(
        deltaT, xcT, BC, A_log, D_skip, zt, ygate_bf);

    // 6. tpre = ygate @ W_out + b_out + x  (2048 x 1024 x 2048), 64x64 (r4 best)
    gemm_bf16<64, 64, 2, 3><<<dim3(1024 / 64, 2048 / 64), blk, 0, stream>>>(
        ygate_bf, W_out_t, b_out, x, tpre, nullptr, 2048, 1024, 2048);

    // 7. LayerNorm
    layernorm_kernel<<<dim3((unsigned)M), blk, 0, stream>>>(tpre, alpha, beta, out);
}

// Round 11
// 264.993 us; speedup vs baseline: 1.0874x; 1.0175x over previous
//
#include <hip/hip_runtime.h>
#include <math.h>

#define B_SZ    2
#define L_SEQ   1024
#define DMODEL  1024
#define DINNER  2048
#define DSTATE  16
#define EPSV    1e-6f

// scan decomposition: 16 channels/block, 64 chunks of 16 steps, 1024 thr/block
#define CCH 64
#define CS  (L_SEQ / CCH)      // 16
#define DT  16
#define SSTR 1040              // CCH*DT + 16 (520 dwords == 8 mod 32, conflict-free combine)

typedef short  bf16x8  __attribute__((ext_vector_type(8)));
typedef float  floatx4 __attribute__((ext_vector_type(4)));
typedef unsigned short ushort8v __attribute__((ext_vector_type(8)));

extern "C" __device__ float __ocml_native_exp2_f32(float);
extern "C" __device__ float __ocml_native_log2_f32(float);

__device__ __forceinline__ float nexp2(float x) { return __ocml_native_exp2_f32(x); }

__device__ __forceinline__ float softplus_f(float v) {
    if (v > 20.f) return v;
    return 0.69314718f * __ocml_native_log2_f32(1.f + nexp2(v * 1.44269504f));
}
__device__ __forceinline__ float silu_f(float z) {
    return z / (1.f + nexp2(z * -1.44269504f));
}

__device__ __forceinline__ unsigned short f2bf(float f) {
    unsigned int u = __float_as_uint(f);
    unsigned int r = (u + 0x7FFFu + ((u >> 16) & 1u)) >> 16;
    return (unsigned short)r;
}
__device__ __forceinline__ float bf2f(unsigned short u) {
    return __uint_as_float(((unsigned int)u) << 16);
}

// async global->LDS, 16 B per lane. LDS dest = wave-uniform base + lane*16.
__device__ __forceinline__ void gload_lds16(const unsigned short* g, unsigned short* l) {
    __builtin_amdgcn_global_load_lds(
        (const __attribute__((address_space(1))) unsigned int*)g,
        (__attribute__((address_space(3))) unsigned int*)l,
        16, 0, 0);
}

// ---------------------------------------------------------------------------
// Fused prep: 3 weight transposes (+cast) and the x cast, one launch.
// ---------------------------------------------------------------------------
__global__ __launch_bounds__(256) void prep_kernel(
    const float* __restrict__ x, unsigned short* __restrict__ x_bf,
    const float* __restrict__ W_in, unsigned short* __restrict__ W_in_t,
    const float* __restrict__ W_dt, unsigned short* __restrict__ W_dt_t,
    const float* __restrict__ W_out, unsigned short* __restrict__ W_out_t)
{
    const int bid = blockIdx.x;
    if (bid >= 10240) {
        const int i = (bid - 10240) * 256 + threadIdx.x;
        float4 v = ((const float4*)x)[i];
        ushort4 o = { f2bf(v.x), f2bf(v.y), f2bf(v.z), f2bf(v.w) };
        ((ushort4*)x_bf)[i] = o;
        return;
    }
    __shared__ float tile[32][33];
    const float* W; unsigned short* Wt; int K, N, t;
    if (bid < 4096)      { W = W_in;  Wt = W_in_t;  K = 1024; N = 4096; t = bid; }
    else if (bid < 8192) { W = W_dt;  Wt = W_dt_t;  K = 2048; N = 2048; t = bid - 4096; }
    else                 { W = W_out; Wt = W_out_t; K = 2048; N = 1024; t = bid - 8192; }
    const int nx = N >> 5;
    const int n0 = (t % nx) * 32;
    const int k0 = (t / nx) * 32;
    const int c = threadIdx.x & 31;
    const int r = threadIdx.x >> 5;
#pragma unroll
    for (int i = 0; i < 4; ++i)
        tile[r + 8 * i][c] = W[(size_t)(k0 + r + 8 * i) * N + n0 + c];
    __syncthreads();
#pragma unroll
    for (int i = 0; i < 4; ++i)
        Wt[(size_t)(n0 + r + 8 * i) * K + k0 + c] = f2bf(tile[c][r + 8 * i]);
}

// ---------------------------------------------------------------------------
// bf16 MFMA GEMM — global_load_lds width-16 staging, swizzle folded into the
// per-lane global address (LDS linear, image identical to reg-staged layout).
// 2x2 waves, wave tile (TM/2)x(TN/2).
// NGEMM != 0: 1D grid; blocks >= NGEMM do a 64x64 bf16 transpose
// (tin [M][DINNER] -> tout [DINNER][M]) reusing As as the LDS tile — hides
// the old transp_bf16 kernel under the dt-GEMM launch (r9-proven fold).
// MODE 0: +bias; 1: softplus(+bias); 2: +bias+resid;
// 4: softplus(+bias) -> bf16 transposed Ct[col][row];
// 5: split: cols<DINNER -> f32 C; cols>=DINNER -> silu -> bf16 zout^T.
// ---------------------------------------------------------------------------
template <int TM, int TN, int MODE, int MINW, int NGEMM>
__global__ __launch_bounds__(256, MINW) void gemm_bf16(
    const unsigned short* __restrict__ A, const unsigned short* __restrict__ Bt,
    const float* __restrict__ bias, const float* __restrict__ resid,
    float* __restrict__ C, unsigned short* __restrict__ zout,
    const unsigned short* __restrict__ tin, unsigned short* __restrict__ tout,
    int M, int N, int K)
{
    constexpr int MI = TM / 32;
    constexpr int NJ = TN / 32;
    constexpr int NINSTR = (TM + TN) / 8;   // 8 rows (1 KB) per instr
    constexpr int NI = NINSTR / 4;          // instrs per wave

    __shared__ unsigned short As[TM * 64];
    __shared__ unsigned short Bs[TN * 64];

    const int tid  = threadIdx.x;

    if (NGEMM != 0 && (int)blockIdx.x >= NGEMM) {
        // ---- transpose block: tin [M][DINNER] -> tout [DINNER][M] ----
        unsigned short (*tile)[66] = (unsigned short (*)[66])As;  // 8.4 KB <= As
        const int t = blockIdx.x - NGEMM;
        const int m0t = (t & 31) * 64;
        const int d0t = (t >> 5) * 64;
        const int r = tid >> 3;
        const int c = (tid & 7) * 8;
#pragma unroll
        for (int i = 0; i < 2; ++i) {
            const int row = r + i * 32;
            ushort8v v = *(const ushort8v*)&tin[(size_t)(m0t + row) * DINNER + d0t + c];
            *(ushort8v*)&tile[row][c] = v;
        }
        __syncthreads();
#pragma unroll
        for (int i = 0; i < 2; ++i) {
            const int dd = r + i * 32;
            ushort8v o;
#pragma unroll
            for (int k = 0; k < 8; ++k) o[k] = tile[c + k][dd];
            *(ushort8v*)&tout[(size_t)(d0t + dd) * (B_SZ * L_SEQ) + m0t + c] = o;
        }
        return;
    }

    const int wave = tid >> 6;
    const int lane = tid & 63;
    const int nx = N / TN;
    const int m0 = (NGEMM != 0 ? (int)blockIdx.x / nx : (int)blockIdx.y) * TM;
    const int n0 = (NGEMM != 0 ? (int)blockIdx.x % nx : (int)blockIdx.x) * TN;
    const int wm = (wave >> 1) * (TM / 2);
    const int wn = (wave & 1) * (TN / 2);
    const int fr = lane & 15;
    const int kg = lane >> 4;

    // per-wave staging descriptors: global src per-lane (swizzled), LDS base uniform
    const unsigned short* gq[NI];
    unsigned short* lq[NI];
#pragma unroll
    for (int q = 0; q < NI; ++q) {
        const int idx = wave * NI + q;
        const int r0i = idx * 8;
        const int sub = lane >> 3;
        const int pos = lane & 7;
        if (r0i < TM) {
            const int row = r0i + sub;
            const int ch  = pos ^ (row & 7);
            gq[q] = A + (size_t)(m0 + row) * K + ch * 8;
            lq[q] = &As[r0i * 64];
        } else {
            const int rb = r0i - TM + sub;
            const int ch = pos ^ (rb & 7);
            gq[q] = Bt + (size_t)(n0 + rb) * K + ch * 8;
            lq[q] = &Bs[(r0i - TM) * 64];
        }
    }

    floatx4 acc[MI][NJ] = {};

#pragma unroll
    for (int q = 0; q < NI; ++q) gload_lds16(gq[q], lq[q]);

    for (int kt = 0; kt < K; kt += 64) {
        __syncthreads();   // vmcnt drained before barrier -> staging visible

#pragma unroll
        for (int ks = 0; ks < 2; ++ks) {
            const int cq = (ks << 2) | kg;
            bf16x8 af[MI], bfv[NJ];
#pragma unroll
            for (int i = 0; i < MI; ++i) {
                const int row = wm + i * 16 + fr;
                af[i] = *(const bf16x8*)&As[row * 64 + ((cq ^ (row & 7)) << 3)];
            }
#pragma unroll
            for (int j = 0; j < NJ; ++j) {
                const int row = wn + j * 16 + fr;
                bfv[j] = *(const bf16x8*)&Bs[row * 64 + ((cq ^ (row & 7)) << 3)];
            }
#pragma unroll
            for (int i = 0; i < MI; ++i)
#pragma unroll
                for (int j = 0; j < NJ; ++j)
                    acc[i][j] = __builtin_amdgcn_mfma_f32_16x16x32_bf16(
                        af[i], bfv[j], acc[i][j], 0, 0, 0);
        }

        if (kt + 64 < K) {
            __syncthreads();   // all reads done before overwrite
#pragma unroll
            for (int q = 0; q < NI; ++q) gload_lds16(gq[q] + kt + 64, lq[q]);
        }
    }

    const int rq = (lane >> 4) * 4;
    if (MODE == 4) {
        unsigned short* Ct = (unsigned short*)C;
#pragma unroll
        for (int i = 0; i < MI; ++i) {
#pragma unroll
            for (int j = 0; j < NJ; ++j) {
                const int col = n0 + wn + j * 16 + fr;
                const float bv = bias[col];
                const int row0 = m0 + wm + i * 16 + rq;
                ushort4 o;
#pragma unroll
                for (int r = 0; r < 4; ++r)
                    (&o.x)[r] = f2bf(softplus_f(acc[i][j][r] + bv));
                *(ushort4*)&Ct[(size_t)col * M + row0] = o;
            }
        }
    } else if (MODE == 5) {
        if (n0 < DINNER) {
#pragma unroll
            for (int i = 0; i < MI; ++i) {
#pragma unroll
                for (int j = 0; j < NJ; ++j) {
                    const int col = n0 + wn + j * 16 + fr;
                    const float bv = bias[col];
#pragma unroll
                    for (int r = 0; r < 4; ++r) {
                        const int row = m0 + wm + i * 16 + rq + r;
                        C[(size_t)row * DINNER + col] = acc[i][j][r] + bv;
                    }
                }
            }
        } else {
#pragma unroll
            for (int i = 0; i < MI; ++i) {
#pragma unroll
                for (int j = 0; j < NJ; ++j) {
                    const int col = n0 + wn + j * 16 + fr;
                    const float bv = bias[col];
                    const int row0 = m0 + wm + i * 16 + rq;
                    ushort4 o;
#pragma unroll
                    for (int r = 0; r < 4; ++r)
                        (&o.x)[r] = f2bf(silu_f(acc[i][j][r] + bv));
                    *(ushort4*)&zout[(size_t)(col - DINNER) * M + row0] = o;
                }
            }
        }
    } else {
#pragma unroll
        for (int i = 0; i < MI; ++i) {
#pragma unroll
            for (int j = 0; j < NJ; ++j) {
                const int col = n0 + wn + j * 16 + fr;
                const float bv = bias[col];
#pragma unroll
                for (int r = 0; r < 4; ++r) {
                    const int row = m0 + wm + i * 16 + rq + r;
                    float v = acc[i][j][r] + bv;
                    if (MODE == 1) {
                        v = softplus_f(v);
                    } else if (MODE == 2) {
                        v += resid[(size_t)row * N + col];
                    }
                    C[(size_t)row * N + col] = v;
                }
            }
        }
    }
}

// ---------------------------------------------------------------------------
// Fused depthwise causal conv1d(k=4) + SiLU + x_proj. bf16 x_conv only.
// ---------------------------------------------------------------------------
#define CROWS 4
__global__ __launch_bounds__(256) void conv_xproj(
    const float* __restrict__ x_in, const float* __restrict__ conv_w,
    const float* __restrict__ conv_b, const float* __restrict__ W_xp,
    const float* __restrict__ b_xp,
    unsigned short* __restrict__ x_conv_bf, float* __restrict__ BC)
{
    __shared__ float sxc[CROWS][DINNER];   // 32 KB
    __shared__ float red[8][CROWS][32];    // 4 KB

    const int tid = threadIdx.x;
    const int r0 = blockIdx.x * CROWS;
    const int c8 = tid * 8;

    float wt[8][4];
#pragma unroll
    for (int ci = 0; ci < 8; ++ci) {
        float4 w4 = *(const float4*)&conv_w[(c8 + ci) * 4];
        wt[ci][0] = w4.x; wt[ci][1] = w4.y; wt[ci][2] = w4.z; wt[ci][3] = w4.w;
    }
    float cb[8];
    *(float4*)&cb[0] = *(const float4*)&conv_b[c8];
    *(float4*)&cb[4] = *(const float4*)&conv_b[c8 + 4];

#pragma unroll
    for (int rr = 0; rr < CROWS; ++rr) {
        const int row = r0 + rr;
        const int l = row & (L_SEQ - 1);
        float acc[8];
#pragma unroll
        for (int ci = 0; ci < 8; ++ci) acc[ci] = cb[ci];
#pragma unroll
        for (int h = 0; h < 4; ++h) {
            const int lsrc = l - 3 + h;
            if (lsrc >= 0) {
                float4 a = *(const float4*)&x_in[(size_t)(row - 3 + h) * DINNER + c8];
                float4 b = *(const float4*)&x_in[(size_t)(row - 3 + h) * DINNER + c8 + 4];
                acc[0] += a.x * wt[0][h]; acc[1] += a.y * wt[1][h];
                acc[2] += a.z * wt[2][h]; acc[3] += a.w * wt[3][h];
                acc[4] += b.x * wt[4][h]; acc[5] += b.y * wt[5][h];
                acc[6] += b.z * wt[6][h]; acc[7] += b.w * wt[7][h];
            }
        }
        float o[8];
        ushort8v ob;
#pragma unroll
        for (int ci = 0; ci < 8; ++ci) {
            o[ci] = silu_f(acc[ci]);
            sxc[rr][c8 + ci] = o[ci];
            ob[ci] = (short)f2bf(o[ci]);
        }
        *(ushort8v*)&x_conv_bf[(size_t)row * DINNER + c8] = ob;
    }
    __syncthreads();

    const int n = tid & 31;
    const int g = tid >> 5;
    float p[CROWS] = {};
    const int k0 = g * 256;
#pragma unroll 4
    for (int k = k0; k < k0 + 256; ++k) {
        const float wv = W_xp[k * 32 + n];
        p[0] += sxc[0][k] * wv;
        p[1] += sxc[1][k] * wv;
        p[2] += sxc[2][k] * wv;
        p[3] += sxc[3][k] * wv;
    }
#pragma unroll
    for (int rr = 0; rr < CROWS; ++rr) red[g][rr][n] = p[rr];
    __syncthreads();
    if (tid < CROWS * 32) {
        const int rr = tid >> 5;
        const int n2 = tid & 31;
        float s = b_xp[n2];
#pragma unroll
        for (int gg = 0; gg < 8; ++gg) s += red[gg][rr][n2];
        BC[(size_t)(r0 + rr) * 32 + n2] = s;
    }
}

// ---------------------------------------------------------------------------
// Chunked two-pass selective scan (round-6 proven: DT=16/CCH=64, 37 KB LDS,
// conflict-free combine, all sequential inputs coalesced bf16x8 [D][B*L]).
// ---------------------------------------------------------------------------
__global__ __launch_bounds__(1024, 4) void scan_kernel(
    const unsigned short* __restrict__ deltaT,
    const unsigned short* __restrict__ xcT,
    const float* __restrict__ BC, const float* __restrict__ A_log,
    const float* __restrict__ D_skip, const unsigned short* __restrict__ zt,
    unsigned short* __restrict__ y_bf)
{
    __shared__ unsigned short sH[DSTATE * SSTR];   // 33.3 KB
    __shared__ float sDsum[CCH * DT];              // 4 KB

    const int tid = threadIdx.x;
    const int dl  = tid & (DT - 1);
    const int c   = tid >> 4;
    const int b   = blockIdx.x >> 7;
    const int d0  = (blockIdx.x & 127) * DT;
    const int d   = d0 + dl;

    const int l0 = c * CS;
    const int row0 = b * L_SEQ + l0;

    const unsigned short* dpt = deltaT + (size_t)d * (B_SZ * L_SEQ) + row0;
    bf16x8 dv0 = *(const bf16x8*)dpt;
    bf16x8 dv1 = *(const bf16x8*)(dpt + 8);
    const unsigned short* xpt = xcT + (size_t)d * (B_SZ * L_SEQ) + row0;
    bf16x8 xv0 = *(const bf16x8*)xpt;
    bf16x8 xv1 = *(const bf16x8*)(xpt + 8);
    const unsigned short* gpt = zt + (size_t)d * (B_SZ * L_SEQ) + row0;
    bf16x8 gv0 = *(const bf16x8*)gpt;
    bf16x8 gv1 = *(const bf16x8*)(gpt + 8);

    float Al[DSTATE];
#pragma unroll
    for (int s = 0; s < DSTATE; ++s)
        Al[s] = -__expf(A_log[d * DSTATE + s]) * 1.44269504f;
    const float Dsk = D_skip[d];

    float dts[CS], xcs[CS];
    float dsum = 0.f;
#pragma unroll
    for (int k = 0; k < 8; ++k) {
        dts[k]     = bf2f((unsigned short)dv0[k]);
        dts[8 + k] = bf2f((unsigned short)dv1[k]);
        xcs[k]     = bf2f((unsigned short)xv0[k]);
        xcs[8 + k] = bf2f((unsigned short)xv1[k]);
    }
#pragma unroll
    for (int k = 0; k < CS; ++k) dsum += dts[k];

    float h[DSTATE];
#pragma unroll
    for (int s = 0; s < DSTATE; ++s) h[s] = 0.f;

    const float* bcp = BC + (size_t)row0 * 32;

    // ---- pass 1: chunk summaries from h=0 ----
#pragma unroll 4
    for (int j = 0; j < CS; ++j) {
        const float dt = dts[j];
        const float xc = xcs[j];
        float Bv[DSTATE];
        *(float4*)&Bv[0]  = *(const float4*)(bcp + j * 32 + 0);
        *(float4*)&Bv[4]  = *(const float4*)(bcp + j * 32 + 4);
        *(float4*)&Bv[8]  = *(const float4*)(bcp + j * 32 + 8);
        *(float4*)&Bv[12] = *(const float4*)(bcp + j * 32 + 12);
        const float dlx = dt * xc;
#pragma unroll
        for (int s = 0; s < DSTATE; ++s) {
            const float e = nexp2(dt * Al[s]);
            h[s] = e * h[s] + dlx * Bv[s];
        }
    }
#pragma unroll
    for (int s = 0; s < DSTATE; ++s)
        sH[s * SSTR + tid] = f2bf(h[s]);
    sDsum[tid] = dsum;
    __syncthreads();

    // ---- combine: sequential over chunks, parallel over (s, dl) ----
    if (tid < DSTATE * DT) {
        const int dl2 = tid & (DT - 1);
        const int s2  = tid >> 4;
        const float Alc = -__expf(A_log[(d0 + dl2) * DSTATE + s2]) * 1.44269504f;
        float hh = 0.f;
        for (int c2 = 0; c2 < CCH; ++c2) {
            const int idx = s2 * SSTR + c2 * DT + dl2;
            const float a  = nexp2(Alc * sDsum[c2 * DT + dl2]);
            const float he = bf2f(sH[idx]);
            sH[idx] = f2bf(hh);
            hh = a * hh + he;
        }
    }
    __syncthreads();

#pragma unroll
    for (int s = 0; s < DSTATE; ++s) h[s] = bf2f(sH[s * SSTR + tid]);

    // ---- pass 2: rescan with true h0, fuse D_skip + precomputed gate ----
    unsigned short* yp = y_bf + (size_t)row0 * DINNER + d;
#pragma unroll
    for (int j = 0; j < 8; ++j) {
        const float dt = dts[j];
        const float xc = xcs[j];
        const float g  = bf2f((unsigned short)gv0[j]);
        float Bv[DSTATE], Cv[DSTATE];
        *(float4*)&Bv[0]  = *(const float4*)(bcp + j * 32 + 0);
        *(float4*)&Bv[4]  = *(const float4*)(bcp + j * 32 + 4);
        *(float4*)&Bv[8]  = *(const float4*)(bcp + j * 32 + 8);
        *(float4*)&Bv[12] = *(const float4*)(bcp + j * 32 + 12);
        *(float4*)&Cv[0]  = *(const float4*)(bcp + j * 32 + 16);
        *(float4*)&Cv[4]  = *(const float4*)(bcp + j * 32 + 20);
        *(float4*)&Cv[8]  = *(const float4*)(bcp + j * 32 + 24);
        *(float4*)&Cv[12] = *(const float4*)(bcp + j * 32 + 28);
        const float dlx = dt * xc;
        float y = Dsk * xc;
#pragma unroll
        for (int s = 0; s < DSTATE; ++s) {
            const float e = nexp2(dt * Al[s]);
            h[s] = e * h[s] + dlx * Bv[s];
            y += h[s] * Cv[s];
        }
        yp[j * DINNER] = f2bf(y * g);
    }
#pragma unroll
    for (int j2 = 0; j2 < 8; ++j2) {
        const int j = j2 + 8;
        const float dt = dts[j];
        const float xc = xcs[j];
        const float g  = bf2f((unsigned short)gv1[j2]);
        float Bv[DSTATE], Cv[DSTATE];
        *(float4*)&Bv[0]  = *(const float4*)(bcp + j * 32 + 0);
        *(float4*)&Bv[4]  = *(const float4*)(bcp + j * 32 + 4);
        *(float4*)&Bv[8]  = *(const float4*)(bcp + j * 32 + 8);
        *(float4*)&Bv[12] = *(const float4*)(bcp + j * 32 + 12);
        *(float4*)&Cv[0]  = *(const float4*)(bcp + j * 32 + 16);
        *(float4*)&Cv[4]  = *(const float4*)(bcp + j * 32 + 20);
        *(float4*)&Cv[8]  = *(const float4*)(bcp + j * 32 + 24);
        *(float4*)&Cv[12] = *(const float4*)(bcp + j * 32 + 28);
        const float dlx = dt * xc;
        float y = Dsk * xc;
#pragma unroll
        for (int s = 0; s < DSTATE; ++s) {
            const float e = nexp2(dt * Al[s]);
            h[s] = e * h[s] + dlx * Bv[s];
            y += h[s] * Cv[s];
        }
        yp[j * DINNER] = f2bf(y * g);
    }
}

// ---------------------------------------------------------------------------
// Row LayerNorm: unbiased variance (N-1), eps added to std.
// ---------------------------------------------------------------------------
__global__ __launch_bounds__(256) void layernorm_kernel(
    const float* __restrict__ t, const float* __restrict__ alpha,
    const float* __restrict__ beta, float* __restrict__ out)
{
    __shared__ float sred[4];
    __shared__ float sred2[4];
    const int row = blockIdx.x;
    const int tid = threadIdx.x;
    const float* r = t + (size_t)row * DMODEL;

    float4 v = *(const float4*)&r[tid * 4];
    float lsum = v.x + v.y + v.z + v.w;
#pragma unroll
    for (int m = 1; m < 64; m <<= 1) lsum += __shfl_xor(lsum, m);
    if ((tid & 63) == 0) sred[tid >> 6] = lsum;
    __syncthreads();
    const float mean = (sred[0] + sred[1] + sred[2] + sred[3]) * (1.f / DMODEL);

    const float dx = v.x - mean, dy = v.y - mean, dz = v.z - mean, dw = v.w - mean;
    float ls2 = dx * dx + dy * dy + dz * dz + dw * dw;
#pragma unroll
    for (int m = 1; m < 64; m <<= 1) ls2 += __shfl_xor(ls2, m);
    if ((tid & 63) == 0) sred2[tid >> 6] = ls2;
    __syncthreads();
    const float var = (sred2[0] + sred2[1] + sred2[2] + sred2[3]) * (1.f / (DMODEL - 1));
    const float inv = 1.f / (sqrtf(var) + EPSV);

    float4 a4 = *(const float4*)&alpha[tid * 4];
    float4 b4 = *(const float4*)&beta[tid * 4];
    float4 o;
    o.x = a4.x * dx * inv + b4.x;
    o.y = a4.y * dy * inv + b4.y;
    o.z = a4.z * dz * inv + b4.z;
    o.w = a4.w * dw * inv + b4.w;
    *(float4*)&out[(size_t)row * DMODEL + tid * 4] = o;
}

// ---------------------------------------------------------------------------
extern "C" void kernel_launch(void* const* d_in, const int* in_sizes, int n_in,
                              void* d_out, int out_size, void* d_ws, size_t ws_size,
                              hipStream_t stream)
{
    const float* x      = (const float*)d_in[0];
    const float* W_in   = (const float*)d_in[1];
    const float* b_in   = (const float*)d_in[2];
    const float* conv_w = (const float*)d_in[3];
    const float* conv_b = (const float*)d_in[4];
    const float* W_xp   = (const float*)d_in[5];
    const float* b_xp   = (const float*)d_in[6];
    const float* W_dt   = (const float*)d_in[7];
    const float* b_dt   = (const float*)d_in[8];
    const float* A_log  = (const float*)d_in[9];
    const float* D_skip = (const float*)d_in[10];
    const float* W_out  = (const float*)d_in[11];
    const float* b_out  = (const float*)d_in[12];
    const float* alpha  = (const float*)d_in[13];
    const float* beta   = (const float*)d_in[14];
    float* out = (float*)d_out;

    const size_t M = (size_t)B_SZ * L_SEQ;  // 2048 rows
    char* ws = (char*)d_ws;
    float* x_in    = (float*)(ws + 0);                  // 16 MB (reused as tpre)
    unsigned short* zt = (unsigned short*)(ws + (16u << 20));      // 8 MB, [D][B*L]
    unsigned short* deltaT = (unsigned short*)(ws + (48u << 20));  // 8 MB, [D][B*L]
    float* BC      = (float*)(ws + (64u << 20));        // 0.5 MB
    unsigned short* x_bf       = (unsigned short*)(ws + (64u << 20) + (512u << 10)); // 4 MB
    unsigned short* W_in_t     = (unsigned short*)(ws + (69u << 20));  // 8 MB
    unsigned short* W_dt_t     = (unsigned short*)(ws + (77u << 20));  // 8 MB
    unsigned short* W_out_t    = (unsigned short*)(ws + (85u << 20));  // 4 MB
    unsigned short* x_conv_bf  = (unsigned short*)(ws + (89u << 20));  // 8 MB
    unsigned short* xcT        = (unsigned short*)(ws + (24u << 20));  // 8 MB, [D][B*L]
    unsigned short* ygate_bf   = (unsigned short*)(ws + (77u << 20));  // reuse W_dt_t
    float* tpre = x_in;

    const dim3 blk(256);

    // 0. fused prep: weight transposes + x cast
    prep_kernel<<<dim3(12288), blk, 0, stream>>>(
        x, x_bf, W_in, W_in_t, W_dt, W_dt_t, W_out, W_out_t);

    // 1. xz = x @ W_in + b_in (2048 x 4096 x 1024), 128x128 (r7-proven).
    //    MODE 5: x_in f32 [M][2048]; z half -> silu -> bf16 zt[D][M]
    gemm_bf16<128, 128, 5, 2, 0><<<dim3(4096 / 128, 2048 / 128), blk, 0, stream>>>(
        x_bf, W_in_t, b_in, nullptr, x_in, zt, nullptr, nullptr, 2048, 4096, 1024);

    // 2+3. conv + SiLU + x_proj (fused)
    conv_xproj<<<dim3((unsigned)(M / CROWS)), blk, 0, stream>>>(
        x_in, conv_w, conv_b, W_xp, b_xp, x_conv_bf, BC);

    // 4. deltaT = softplus(x_conv @ W_dt + b_dt)^T -> bf16 [D][B*L], 128x64
    //    + 1024 extra blocks: x_conv [M][D] -> xcT [D][M] (folded transpose)
    gemm_bf16<128, 64, 4, 3, 512><<<dim3(512 + 1024), blk, 0, stream>>>(
        x_conv_bf, W_dt_t, b_dt, nullptr, (float*)deltaT, nullptr,
        x_conv_bf, xcT, 2048, 2048, 2048);

    // 5. chunked two-pass selective scan + D_skip + gate -> bf16
    scan_kernel<<<dim3(B_SZ * (DINNER / DT)), dim3(1024), 0, stream>>>(
        deltaT, xcT, BC, A_log, D_skip, zt, ygate_bf);

    // 6. tpre = ygate @ W_out + b_out + x  (2048 x 1024 x 2048), 64x64 (r4 best)
    gemm_bf16<64, 64, 2, 3, 0><<<dim3(1024 / 64, 2048 / 64), blk, 0, stream>>>(
        ygate_bf, W_out_t, b_out, x, tpre, nullptr, nullptr, nullptr,
        2048, 1024, 2048);

    // 7. LayerNorm
    layernorm_kernel<<<dim3((unsigned)M), blk, 0, stream>>>(tpre, alpha, beta, out);
}

// Round 12
// 264.736 us; speedup vs baseline: 1.0885x; 1.0010x over previous
//
#include <hip/hip_runtime.h>
#include <math.h>

#define B_SZ    2
#define L_SEQ   1024
#define DMODEL  1024
#define DINNER  2048
#define DSTATE  16
#define EPSV    1e-6f

// scan decomposition: 16 channels/block, 64 chunks of 16 steps, 1024 thr/block
#define CCH 64
#define CS  (L_SEQ / CCH)      // 16
#define DT  16
#define SSTR 1040              // CCH*DT + 16 (520 dwords == 8 mod 32, conflict-free combine)

typedef short  bf16x8  __attribute__((ext_vector_type(8)));
typedef float  floatx4 __attribute__((ext_vector_type(4)));
typedef unsigned short ushort8v __attribute__((ext_vector_type(8)));

extern "C" __device__ float __ocml_native_exp2_f32(float);
extern "C" __device__ float __ocml_native_log2_f32(float);

__device__ __forceinline__ float nexp2(float x) { return __ocml_native_exp2_f32(x); }

__device__ __forceinline__ float softplus_f(float v) {
    if (v > 20.f) return v;
    return 0.69314718f * __ocml_native_log2_f32(1.f + nexp2(v * 1.44269504f));
}
__device__ __forceinline__ float silu_f(float z) {
    return z / (1.f + nexp2(z * -1.44269504f));
}

__device__ __forceinline__ unsigned short f2bf(float f) {
    unsigned int u = __float_as_uint(f);
    unsigned int r = (u + 0x7FFFu + ((u >> 16) & 1u)) >> 16;
    return (unsigned short)r;
}
__device__ __forceinline__ float bf2f(unsigned short u) {
    return __uint_as_float(((unsigned int)u) << 16);
}

// async global->LDS, 16 B per lane. LDS dest = wave-uniform base + lane*16.
__device__ __forceinline__ void gload_lds16(const unsigned short* g, unsigned short* l) {
    __builtin_amdgcn_global_load_lds(
        (const __attribute__((address_space(1))) unsigned int*)g,
        (__attribute__((address_space(3))) unsigned int*)l,
        16, 0, 0);
}

// ---------------------------------------------------------------------------
// Prep (shrunk): only what gemm1 needs — W_in transpose (4096 blocks) +
// x cast (2048 blocks). W_dt/W_out transposes ride inside gemm1's launch.
// ---------------------------------------------------------------------------
__global__ __launch_bounds__(256) void prep_kernel(
    const float* __restrict__ x, unsigned short* __restrict__ x_bf,
    const float* __restrict__ W_in, unsigned short* __restrict__ W_in_t)
{
    const int bid = blockIdx.x;
    if (bid >= 4096) {
        const int i = (bid - 4096) * 256 + threadIdx.x;
        float4 v = ((const float4*)x)[i];
        ushort4 o = { f2bf(v.x), f2bf(v.y), f2bf(v.z), f2bf(v.w) };
        ((ushort4*)x_bf)[i] = o;
        return;
    }
    __shared__ float tile[32][33];
    const int K = 1024, N = 4096, t = bid;
    const int nx = N >> 5;
    const int n0 = (t % nx) * 32;
    const int k0 = (t / nx) * 32;
    const int c = threadIdx.x & 31;
    const int r = threadIdx.x >> 5;
#pragma unroll
    for (int i = 0; i < 4; ++i)
        tile[r + 8 * i][c] = W_in[(size_t)(k0 + r + 8 * i) * N + n0 + c];
    __syncthreads();
#pragma unroll
    for (int i = 0; i < 4; ++i)
        W_in_t[(size_t)(n0 + r + 8 * i) * K + k0 + c] = f2bf(tile[c][r + 8 * i]);
}

// ---------------------------------------------------------------------------
// bf16 MFMA GEMM — global_load_lds width-16 staging, swizzle folded into the
// per-lane global address (LDS linear, image identical to reg-staged layout).
// 2x2 waves, wave tile (TM/2)x(TN/2).
// NGEMM != 0: 1D grid; blocks >= NGEMM do folded side-work:
//   XW=0: 64x64 bf16 transpose tin [M][DINNER] -> tout [DINNER][M] (r11 fold)
//   XW=1: f32 weight transposes (W_dt 4096 tiles, then W_out 2048 tiles),
//         riding in gemm1's idle CU capacity (gemm blocks dispatched first).
// MODE 0: +bias; 1: softplus(+bias); 2: +bias+resid;
// 4: softplus(+bias) -> bf16 transposed Ct[col][row];
// 5: split: cols<DINNER -> f32 C; cols>=DINNER -> silu -> bf16 zout^T.
// ---------------------------------------------------------------------------
template <int TM, int TN, int MODE, int MINW, int NGEMM, int XW>
__global__ __launch_bounds__(256, MINW) void gemm_bf16(
    const unsigned short* __restrict__ A, const unsigned short* __restrict__ Bt,
    const float* __restrict__ bias, const float* __restrict__ resid,
    float* __restrict__ C, unsigned short* __restrict__ zout,
    const unsigned short* __restrict__ tin, unsigned short* __restrict__ tout,
    const float* __restrict__ ws1, unsigned short* __restrict__ wd1,
    const float* __restrict__ ws2, unsigned short* __restrict__ wd2,
    int M, int N, int K)
{
    constexpr int MI = TM / 32;
    constexpr int NJ = TN / 32;
    constexpr int NINSTR = (TM + TN) / 8;   // 8 rows (1 KB) per instr
    constexpr int NI = NINSTR / 4;          // instrs per wave

    __shared__ unsigned short As[TM * 64];
    __shared__ unsigned short Bs[TN * 64];

    const int tid  = threadIdx.x;

    if (NGEMM != 0 && (int)blockIdx.x >= NGEMM) {
        if (XW == 0) {
            // ---- bf16 transpose block: tin [M][DINNER] -> tout [DINNER][M] ----
            unsigned short (*tile)[66] = (unsigned short (*)[66])As;  // 8.4 KB <= As
            const int t = blockIdx.x - NGEMM;
            const int m0t = (t & 31) * 64;
            const int d0t = (t >> 5) * 64;
            const int r = tid >> 3;
            const int c = (tid & 7) * 8;
#pragma unroll
            for (int i = 0; i < 2; ++i) {
                const int row = r + i * 32;
                ushort8v v = *(const ushort8v*)&tin[(size_t)(m0t + row) * DINNER + d0t + c];
                *(ushort8v*)&tile[row][c] = v;
            }
            __syncthreads();
#pragma unroll
            for (int i = 0; i < 2; ++i) {
                const int dd = r + i * 32;
                ushort8v o;
#pragma unroll
                for (int k = 0; k < 8; ++k) o[k] = tile[c + k][dd];
                *(ushort8v*)&tout[(size_t)(d0t + dd) * (B_SZ * L_SEQ) + m0t + c] = o;
            }
        } else {
            // ---- f32 weight transpose block (prep fold): W_dt then W_out ----
            float (*tile)[33] = (float (*)[33])As;   // 4.2 KB <= As
            const int t0 = blockIdx.x - NGEMM;
            const float* W; unsigned short* Wt; int K2, N2, t;
            if (t0 < 4096) { W = ws1; Wt = wd1; K2 = 2048; N2 = 2048; t = t0; }
            else           { W = ws2; Wt = wd2; K2 = 2048; N2 = 1024; t = t0 - 4096; }
            const int nx2 = N2 >> 5;
            const int n0t = (t % nx2) * 32;
            const int k0t = (t / nx2) * 32;
            const int cc = tid & 31;
            const int rr = tid >> 5;
#pragma unroll
            for (int i = 0; i < 4; ++i)
                tile[rr + 8 * i][cc] = W[(size_t)(k0t + rr + 8 * i) * N2 + n0t + cc];
            __syncthreads();
#pragma unroll
            for (int i = 0; i < 4; ++i)
                Wt[(size_t)(n0t + rr + 8 * i) * K2 + k0t + cc] = f2bf(tile[cc][rr + 8 * i]);
        }
        return;
    }

    const int wave = tid >> 6;
    const int lane = tid & 63;
    const int nx = N / TN;
    const int m0 = (NGEMM != 0 ? (int)blockIdx.x / nx : (int)blockIdx.y) * TM;
    const int n0 = (NGEMM != 0 ? (int)blockIdx.x % nx : (int)blockIdx.x) * TN;
    const int wm = (wave >> 1) * (TM / 2);
    const int wn = (wave & 1) * (TN / 2);
    const int fr = lane & 15;
    const int kg = lane >> 4;

    // per-wave staging descriptors: global src per-lane (swizzled), LDS base uniform
    const unsigned short* gq[NI];
    unsigned short* lq[NI];
#pragma unroll
    for (int q = 0; q < NI; ++q) {
        const int idx = wave * NI + q;
        const int r0i = idx * 8;
        const int sub = lane >> 3;
        const int pos = lane & 7;
        if (r0i < TM) {
            const int row = r0i + sub;
            const int ch  = pos ^ (row & 7);
            gq[q] = A + (size_t)(m0 + row) * K + ch * 8;
            lq[q] = &As[r0i * 64];
        } else {
            const int rb = r0i - TM + sub;
            const int ch = pos ^ (rb & 7);
            gq[q] = Bt + (size_t)(n0 + rb) * K + ch * 8;
            lq[q] = &Bs[(r0i - TM) * 64];
        }
    }

    floatx4 acc[MI][NJ] = {};

#pragma unroll
    for (int q = 0; q < NI; ++q) gload_lds16(gq[q], lq[q]);

    for (int kt = 0; kt < K; kt += 64) {
        __syncthreads();   // vmcnt drained before barrier -> staging visible

#pragma unroll
        for (int ks = 0; ks < 2; ++ks) {
            const int cq = (ks << 2) | kg;
            bf16x8 af[MI], bfv[NJ];
#pragma unroll
            for (int i = 0; i < MI; ++i) {
                const int row = wm + i * 16 + fr;
                af[i] = *(const bf16x8*)&As[row * 64 + ((cq ^ (row & 7)) << 3)];
            }
#pragma unroll
            for (int j = 0; j < NJ; ++j) {
                const int row = wn + j * 16 + fr;
                bfv[j] = *(const bf16x8*)&Bs[row * 64 + ((cq ^ (row & 7)) << 3)];
            }
#pragma unroll
            for (int i = 0; i < MI; ++i)
#pragma unroll
                for (int j = 0; j < NJ; ++j)
                    acc[i][j] = __builtin_amdgcn_mfma_f32_16x16x32_bf16(
                        af[i], bfv[j], acc[i][j], 0, 0, 0);
        }

        if (kt + 64 < K) {
            __syncthreads();   // all reads done before overwrite
#pragma unroll
            for (int q = 0; q < NI; ++q) gload_lds16(gq[q] + kt + 64, lq[q]);
        }
    }

    const int rq = (lane >> 4) * 4;
    if (MODE == 4) {
        unsigned short* Ct = (unsigned short*)C;
#pragma unroll
        for (int i = 0; i < MI; ++i) {
#pragma unroll
            for (int j = 0; j < NJ; ++j) {
                const int col = n0 + wn + j * 16 + fr;
                const float bv = bias[col];
                const int row0 = m0 + wm + i * 16 + rq;
                ushort4 o;
#pragma unroll
                for (int r = 0; r < 4; ++r)
                    (&o.x)[r] = f2bf(softplus_f(acc[i][j][r] + bv));
                *(ushort4*)&Ct[(size_t)col * M + row0] = o;
            }
        }
    } else if (MODE == 5) {
        if (n0 < DINNER) {
#pragma unroll
            for (int i = 0; i < MI; ++i) {
#pragma unroll
                for (int j = 0; j < NJ; ++j) {
                    const int col = n0 + wn + j * 16 + fr;
                    const float bv = bias[col];
#pragma unroll
                    for (int r = 0; r < 4; ++r) {
                        const int row = m0 + wm + i * 16 + rq + r;
                        C[(size_t)row * DINNER + col] = acc[i][j][r] + bv;
                    }
                }
            }
        } else {
#pragma unroll
            for (int i = 0; i < MI; ++i) {
#pragma unroll
                for (int j = 0; j < NJ; ++j) {
                    const int col = n0 + wn + j * 16 + fr;
                    const float bv = bias[col];
                    const int row0 = m0 + wm + i * 16 + rq;
                    ushort4 o;
#pragma unroll
                    for (int r = 0; r < 4; ++r)
                        (&o.x)[r] = f2bf(silu_f(acc[i][j][r] + bv));
                    *(ushort4*)&zout[(size_t)(col - DINNER) * M + row0] = o;
                }
            }
        }
    } else {
#pragma unroll
        for (int i = 0; i < MI; ++i) {
#pragma unroll
            for (int j = 0; j < NJ; ++j) {
                const int col = n0 + wn + j * 16 + fr;
                const float bv = bias[col];
#pragma unroll
                for (int r = 0; r < 4; ++r) {
                    const int row = m0 + wm + i * 16 + rq + r;
                    float v = acc[i][j][r] + bv;
                    if (MODE == 1) {
                        v = softplus_f(v);
                    } else if (MODE == 2) {
                        v += resid[(size_t)row * N + col];
                    }
                    C[(size_t)row * N + col] = v;
                }
            }
        }
    }
}

// ---------------------------------------------------------------------------
// Fused depthwise causal conv1d(k=4) + SiLU + x_proj. bf16 x_conv only.
// ---------------------------------------------------------------------------
#define CROWS 4
__global__ __launch_bounds__(256) void conv_xproj(
    const float* __restrict__ x_in, const float* __restrict__ conv_w,
    const float* __restrict__ conv_b, const float* __restrict__ W_xp,
    const float* __restrict__ b_xp,
    unsigned short* __restrict__ x_conv_bf, float* __restrict__ BC)
{
    __shared__ float sxc[CROWS][DINNER];   // 32 KB
    __shared__ float red[8][CROWS][32];    // 4 KB

    const int tid = threadIdx.x;
    const int r0 = blockIdx.x * CROWS;
    const int c8 = tid * 8;

    float wt[8][4];
#pragma unroll
    for (int ci = 0; ci < 8; ++ci) {
        float4 w4 = *(const float4*)&conv_w[(c8 + ci) * 4];
        wt[ci][0] = w4.x; wt[ci][1] = w4.y; wt[ci][2] = w4.z; wt[ci][3] = w4.w;
    }
    float cb[8];
    *(float4*)&cb[0] = *(const float4*)&conv_b[c8];
    *(float4*)&cb[4] = *(const float4*)&conv_b[c8 + 4];

#pragma unroll
    for (int rr = 0; rr < CROWS; ++rr) {
        const int row = r0 + rr;
        const int l = row & (L_SEQ - 1);
        float acc[8];
#pragma unroll
        for (int ci = 0; ci < 8; ++ci) acc[ci] = cb[ci];
#pragma unroll
        for (int h = 0; h < 4; ++h) {
            const int lsrc = l - 3 + h;
            if (lsrc >= 0) {
                float4 a = *(const float4*)&x_in[(size_t)(row - 3 + h) * DINNER + c8];
                float4 b = *(const float4*)&x_in[(size_t)(row - 3 + h) * DINNER + c8 + 4];
                acc[0] += a.x * wt[0][h]; acc[1] += a.y * wt[1][h];
                acc[2] += a.z * wt[2][h]; acc[3] += a.w * wt[3][h];
                acc[4] += b.x * wt[4][h]; acc[5] += b.y * wt[5][h];
                acc[6] += b.z * wt[6][h]; acc[7] += b.w * wt[7][h];
            }
        }
        float o[8];
        ushort8v ob;
#pragma unroll
        for (int ci = 0; ci < 8; ++ci) {
            o[ci] = silu_f(acc[ci]);
            sxc[rr][c8 + ci] = o[ci];
            ob[ci] = (short)f2bf(o[ci]);
        }
        *(ushort8v*)&x_conv_bf[(size_t)row * DINNER + c8] = ob;
    }
    __syncthreads();

    const int n = tid & 31;
    const int g = tid >> 5;
    float p[CROWS] = {};
    const int k0 = g * 256;
#pragma unroll 4
    for (int k = k0; k < k0 + 256; ++k) {
        const float wv = W_xp[k * 32 + n];
        p[0] += sxc[0][k] * wv;
        p[1] += sxc[1][k] * wv;
        p[2] += sxc[2][k] * wv;
        p[3] += sxc[3][k] * wv;
    }
#pragma unroll
    for (int rr = 0; rr < CROWS; ++rr) red[g][rr][n] = p[rr];
    __syncthreads();
    if (tid < CROWS * 32) {
        const int rr = tid >> 5;
        const int n2 = tid & 31;
        float s = b_xp[n2];
#pragma unroll
        for (int gg = 0; gg < 8; ++gg) s += red[gg][rr][n2];
        BC[(size_t)(r0 + rr) * 32 + n2] = s;
    }
}

// ---------------------------------------------------------------------------
// Chunked two-pass selective scan (round-6 proven: DT=16/CCH=64, 37 KB LDS,
// conflict-free combine, all sequential inputs coalesced bf16x8 [D][B*L]).
// ---------------------------------------------------------------------------
__global__ __launch_bounds__(1024, 4) void scan_kernel(
    const unsigned short* __restrict__ deltaT,
    const unsigned short* __restrict__ xcT,
    const float* __restrict__ BC, const float* __restrict__ A_log,
    const float* __restrict__ D_skip, const unsigned short* __restrict__ zt,
    unsigned short* __restrict__ y_bf)
{
    __shared__ unsigned short sH[DSTATE * SSTR];   // 33.3 KB
    __shared__ float sDsum[CCH * DT];              // 4 KB

    const int tid = threadIdx.x;
    const int dl  = tid & (DT - 1);
    const int c   = tid >> 4;
    const int b   = blockIdx.x >> 7;
    const int d0  = (blockIdx.x & 127) * DT;
    const int d   = d0 + dl;

    const int l0 = c * CS;
    const int row0 = b * L_SEQ + l0;

    const unsigned short* dpt = deltaT + (size_t)d * (B_SZ * L_SEQ) + row0;
    bf16x8 dv0 = *(const bf16x8*)dpt;
    bf16x8 dv1 = *(const bf16x8*)(dpt + 8);
    const unsigned short* xpt = xcT + (size_t)d * (B_SZ * L_SEQ) + row0;
    bf16x8 xv0 = *(const bf16x8*)xpt;
    bf16x8 xv1 = *(const bf16x8*)(xpt + 8);
    const unsigned short* gpt = zt + (size_t)d * (B_SZ * L_SEQ) + row0;
    bf16x8 gv0 = *(const bf16x8*)gpt;
    bf16x8 gv1 = *(const bf16x8*)(gpt + 8);

    float Al[DSTATE];
#pragma unroll
    for (int s = 0; s < DSTATE; ++s)
        Al[s] = -__expf(A_log[d * DSTATE + s]) * 1.44269504f;
    const float Dsk = D_skip[d];

    float dts[CS], xcs[CS];
    float dsum = 0.f;
#pragma unroll
    for (int k = 0; k < 8; ++k) {
        dts[k]     = bf2f((unsigned short)dv0[k]);
        dts[8 + k] = bf2f((unsigned short)dv1[k]);
        xcs[k]     = bf2f((unsigned short)xv0[k]);
        xcs[8 + k] = bf2f((unsigned short)xv1[k]);
    }
#pragma unroll
    for (int k = 0; k < CS; ++k) dsum += dts[k];

    float h[DSTATE];
#pragma unroll
    for (int s = 0; s < DSTATE; ++s) h[s] = 0.f;

    const float* bcp = BC + (size_t)row0 * 32;

    // ---- pass 1: chunk summaries from h=0 ----
#pragma unroll 4
    for (int j = 0; j < CS; ++j) {
        const float dt = dts[j];
        const float xc = xcs[j];
        float Bv[DSTATE];
        *(float4*)&Bv[0]  = *(const float4*)(bcp + j * 32 + 0);
        *(float4*)&Bv[4]  = *(const float4*)(bcp + j * 32 + 4);
        *(float4*)&Bv[8]  = *(const float4*)(bcp + j * 32 + 8);
        *(float4*)&Bv[12] = *(const float4*)(bcp + j * 32 + 12);
        const float dlx = dt * xc;
#pragma unroll
        for (int s = 0; s < DSTATE; ++s) {
            const float e = nexp2(dt * Al[s]);
            h[s] = e * h[s] + dlx * Bv[s];
        }
    }
#pragma unroll
    for (int s = 0; s < DSTATE; ++s)
        sH[s * SSTR + tid] = f2bf(h[s]);
    sDsum[tid] = dsum;
    __syncthreads();

    // ---- combine: sequential over chunks, parallel over (s, dl) ----
    if (tid < DSTATE * DT) {
        const int dl2 = tid & (DT - 1);
        const int s2  = tid >> 4;
        const float Alc = -__expf(A_log[(d0 + dl2) * DSTATE + s2]) * 1.44269504f;
        float hh = 0.f;
        for (int c2 = 0; c2 < CCH; ++c2) {
            const int idx = s2 * SSTR + c2 * DT + dl2;
            const float a  = nexp2(Alc * sDsum[c2 * DT + dl2]);
            const float he = bf2f(sH[idx]);
            sH[idx] = f2bf(hh);
            hh = a * hh + he;
        }
    }
    __syncthreads();

#pragma unroll
    for (int s = 0; s < DSTATE; ++s) h[s] = bf2f(sH[s * SSTR + tid]);

    // ---- pass 2: rescan with true h0, fuse D_skip + precomputed gate ----
    unsigned short* yp = y_bf + (size_t)row0 * DINNER + d;
#pragma unroll
    for (int j = 0; j < 8; ++j) {
        const float dt = dts[j];
        const float xc = xcs[j];
        const float g  = bf2f((unsigned short)gv0[j]);
        float Bv[DSTATE], Cv[DSTATE];
        *(float4*)&Bv[0]  = *(const float4*)(bcp + j * 32 + 0);
        *(float4*)&Bv[4]  = *(const float4*)(bcp + j * 32 + 4);
        *(float4*)&Bv[8]  = *(const float4*)(bcp + j * 32 + 8);
        *(float4*)&Bv[12] = *(const float4*)(bcp + j * 32 + 12);
        *(float4*)&Cv[0]  = *(const float4*)(bcp + j * 32 + 16);
        *(float4*)&Cv[4]  = *(const float4*)(bcp + j * 32 + 20);
        *(float4*)&Cv[8]  = *(const float4*)(bcp + j * 32 + 24);
        *(float4*)&Cv[12] = *(const float4*)(bcp + j * 32 + 28);
        const float dlx = dt * xc;
        float y = Dsk * xc;
#pragma unroll
        for (int s = 0; s < DSTATE; ++s) {
            const float e = nexp2(dt * Al[s]);
            h[s] = e * h[s] + dlx * Bv[s];
            y += h[s] * Cv[s];
        }
        yp[j * DINNER] = f2bf(y * g);
    }
#pragma unroll
    for (int j2 = 0; j2 < 8; ++j2) {
        const int j = j2 + 8;
        const float dt = dts[j];
        const float xc = xcs[j];
        const float g  = bf2f((unsigned short)gv1[j2]);
        float Bv[DSTATE], Cv[DSTATE];
        *(float4*)&Bv[0]  = *(const float4*)(bcp + j * 32 + 0);
        *(float4*)&Bv[4]  = *(const float4*)(bcp + j * 32 + 4);
        *(float4*)&Bv[8]  = *(const float4*)(bcp + j * 32 + 8);
        *(float4*)&Bv[12] = *(const float4*)(bcp + j * 32 + 12);
        *(float4*)&Cv[0]  = *(const float4*)(bcp + j * 32 + 16);
        *(float4*)&Cv[4]  = *(const float4*)(bcp + j * 32 + 20);
        *(float4*)&Cv[8]  = *(const float4*)(bcp + j * 32 + 24);
        *(float4*)&Cv[12] = *(const float4*)(bcp + j * 32 + 28);
        const float dlx = dt * xc;
        float y = Dsk * xc;
#pragma unroll
        for (int s = 0; s < DSTATE; ++s) {
            const float e = nexp2(dt * Al[s]);
            h[s] = e * h[s] + dlx * Bv[s];
            y += h[s] * Cv[s];
        }
        yp[j * DINNER] = f2bf(y * g);
    }
}

// ---------------------------------------------------------------------------
// Row LayerNorm: unbiased variance (N-1), eps added to std.
// ---------------------------------------------------------------------------
__global__ __launch_bounds__(256) void layernorm_kernel(
    const float* __restrict__ t, const float* __restrict__ alpha,
    const float* __restrict__ beta, float* __restrict__ out)
{
    __shared__ float sred[4];
    __shared__ float sred2[4];
    const int row = blockIdx.x;
    const int tid = threadIdx.x;
    const float* r = t + (size_t)row * DMODEL;

    float4 v = *(const float4*)&r[tid * 4];
    float lsum = v.x + v.y + v.z + v.w;
#pragma unroll
    for (int m = 1; m < 64; m <<= 1) lsum += __shfl_xor(lsum, m);
    if ((tid & 63) == 0) sred[tid >> 6] = lsum;
    __syncthreads();
    const float mean = (sred[0] + sred[1] + sred[2] + sred[3]) * (1.f / DMODEL);

    const float dx = v.x - mean, dy = v.y - mean, dz = v.z - mean, dw = v.w - mean;
    float ls2 = dx * dx + dy * dy + dz * dz + dw * dw;
#pragma unroll
    for (int m = 1; m < 64; m <<= 1) ls2 += __shfl_xor(ls2, m);
    if ((tid & 63) == 0) sred2[tid >> 6] = ls2;
    __syncthreads();
    const float var = (sred2[0] + sred2[1] + sred2[2] + sred2[3]) * (1.f / (DMODEL - 1));
    const float inv = 1.f / (sqrtf(var) + EPSV);

    float4 a4 = *(const float4*)&alpha[tid * 4];
    float4 b4 = *(const float4*)&beta[tid * 4];
    float4 o;
    o.x = a4.x * dx * inv + b4.x;
    o.y = a4.y * dy * inv + b4.y;
    o.z = a4.z * dz * inv + b4.z;
    o.w = a4.w * dw * inv + b4.w;
    *(float4*)&out[(size_t)row * DMODEL + tid * 4] = o;
}

// ---------------------------------------------------------------------------
extern "C" void kernel_launch(void* const* d_in, const int* in_sizes, int n_in,
                              void* d_out, int out_size, void* d_ws, size_t ws_size,
                              hipStream_t stream)
{
    const float* x      = (const float*)d_in[0];
    const float* W_in   = (const float*)d_in[1];
    const float* b_in   = (const float*)d_in[2];
    const float* conv_w = (const float*)d_in[3];
    const float* conv_b = (const float*)d_in[4];
    const float* W_xp   = (const float*)d_in[5];
    const float* b_xp   = (const float*)d_in[6];
    const float* W_dt   = (const float*)d_in[7];
    const float* b_dt   = (const float*)d_in[8];
    const float* A_log  = (const float*)d_in[9];
    const float* D_skip = (const float*)d_in[10];
    const float* W_out  = (const float*)d_in[11];
    const float* b_out  = (const float*)d_in[12];
    const float* alpha  = (const float*)d_in[13];
    const float* beta   = (const float*)d_in[14];
    float* out = (float*)d_out;

    const size_t M = (size_t)B_SZ * L_SEQ;  // 2048 rows
    char* ws = (char*)d_ws;
    float* x_in    = (float*)(ws + 0);                  // 16 MB (reused as tpre)
    unsigned short* zt = (unsigned short*)(ws + (16u << 20));      // 8 MB, [D][B*L]
    unsigned short* deltaT = (unsigned short*)(ws + (48u << 20));  // 8 MB, [D][B*L]
    float* BC      = (float*)(ws + (64u << 20));        // 0.5 MB
    unsigned short* x_bf       = (unsigned short*)(ws + (64u << 20) + (512u << 10)); // 4 MB
    unsigned short* W_in_t     = (unsigned short*)(ws + (69u << 20));  // 8 MB
    unsigned short* W_dt_t     = (unsigned short*)(ws + (77u << 20));  // 8 MB
    unsigned short* W_out_t    = (unsigned short*)(ws + (85u << 20));  // 4 MB
    unsigned short* x_conv_bf  = (unsigned short*)(ws + (89u << 20));  // 8 MB
    unsigned short* xcT        = (unsigned short*)(ws + (24u << 20));  // 8 MB, [D][B*L]
    unsigned short* ygate_bf   = (unsigned short*)(ws + (77u << 20));  // reuse W_dt_t
    float* tpre = x_in;

    const dim3 blk(256);

    // 0. prep (shrunk): W_in transpose + x cast only (6144 blocks)
    prep_kernel<<<dim3(6144), blk, 0, stream>>>(x, x_bf, W_in, W_in_t);

    // 1. xz = x @ W_in + b_in (2048 x 4096 x 1024), 128x128 (r7-proven).
    //    MODE 5: x_in f32 [M][2048]; z half -> silu -> bf16 zt[D][M].
    //    + 6144 rider blocks transpose W_dt -> W_dt_t and W_out -> W_out_t
    //    in gemm1's idle CU capacity (gemm blocks first in dispatch order).
    gemm_bf16<128, 128, 5, 2, 512, 1><<<dim3(512 + 6144), blk, 0, stream>>>(
        x_bf, W_in_t, b_in, nullptr, x_in, zt, nullptr, nullptr,
        W_dt, W_dt_t, W_out, W_out_t, 2048, 4096, 1024);

    // 2+3. conv + SiLU + x_proj (fused)
    conv_xproj<<<dim3((unsigned)(M / CROWS)), blk, 0, stream>>>(
        x_in, conv_w, conv_b, W_xp, b_xp, x_conv_bf, BC);

    // 4. deltaT = softplus(x_conv @ W_dt + b_dt)^T -> bf16 [D][B*L], 128x64
    //    + 1024 rider blocks: x_conv [M][D] -> xcT [D][M] (r11-proven fold)
    gemm_bf16<128, 64, 4, 3, 512, 0><<<dim3(512 + 1024), blk, 0, stream>>>(
        x_conv_bf, W_dt_t, b_dt, nullptr, (float*)deltaT, nullptr,
        x_conv_bf, xcT, nullptr, nullptr, nullptr, nullptr, 2048, 2048, 2048);

    // 5. chunked two-pass selective scan + D_skip + gate -> bf16
    scan_kernel<<<dim3(B_SZ * (DINNER / DT)), dim3(1024), 0, stream>>>(
        deltaT, xcT, BC, A_log, D_skip, zt, ygate_bf);

    // 6. tpre = ygate @ W_out + b_out + x  (2048 x 1024 x 2048), 64x64 (r4 best)
    gemm_bf16<64, 64, 2, 3, 0, 0><<<dim3(1024 / 64, 2048 / 64), blk, 0, stream>>>(
        ygate_bf, W_out_t, b_out, x, tpre, nullptr, nullptr, nullptr,
        nullptr, nullptr, nullptr, nullptr, 2048, 1024, 2048);

    // 7. LayerNorm
    layernorm_kernel<<<dim3((unsigned)M), blk, 0, stream>>>(tpre, alpha, beta, out);
}

// Round 13
// 263.291 us; speedup vs baseline: 1.0945x; 1.0055x over previous
//
#include <hip/hip_runtime.h>
#include <math.h>

#define B_SZ    2
#define L_SEQ   1024
#define DMODEL  1024
#define DINNER  2048
#define DSTATE  16
#define EPSV    1e-6f

// scan decomposition: 16 channels/block, 64 chunks of 16 steps, 1024 thr/block
#define CCH 64
#define CS  (L_SEQ / CCH)      // 16
#define DT  16
#define SSTR 1040              // CCH*DT + 16 (520 dwords == 8 mod 32, conflict-free combine)

typedef short  bf16x8  __attribute__((ext_vector_type(8)));
typedef float  floatx4 __attribute__((ext_vector_type(4)));
typedef unsigned short ushort8v __attribute__((ext_vector_type(8)));

extern "C" __device__ float __ocml_native_exp2_f32(float);
extern "C" __device__ float __ocml_native_log2_f32(float);

__device__ __forceinline__ float nexp2(float x) { return __ocml_native_exp2_f32(x); }

__device__ __forceinline__ float softplus_f(float v) {
    if (v > 20.f) return v;
    return 0.69314718f * __ocml_native_log2_f32(1.f + nexp2(v * 1.44269504f));
}
__device__ __forceinline__ float silu_f(float z) {
    return z / (1.f + nexp2(z * -1.44269504f));
}

__device__ __forceinline__ unsigned short f2bf(float f) {
    unsigned int u = __float_as_uint(f);
    unsigned int r = (u + 0x7FFFu + ((u >> 16) & 1u)) >> 16;
    return (unsigned short)r;
}
__device__ __forceinline__ float bf2f(unsigned short u) {
    return __uint_as_float(((unsigned int)u) << 16);
}

// async global->LDS, 16 B per lane. LDS dest = wave-uniform base + lane*16.
__device__ __forceinline__ void gload_lds16(const unsigned short* g, unsigned short* l) {
    __builtin_amdgcn_global_load_lds(
        (const __attribute__((address_space(1))) unsigned int*)g,
        (__attribute__((address_space(3))) unsigned int*)l,
        16, 0, 0);
}

// ---------------------------------------------------------------------------
// Prep (shrunk): only what gemm1 needs — W_in transpose (4096 blocks) +
// x cast (2048 blocks). W_dt/W_out transposes ride inside gemm1's launch.
// ---------------------------------------------------------------------------
__global__ __launch_bounds__(256) void prep_kernel(
    const float* __restrict__ x, unsigned short* __restrict__ x_bf,
    const float* __restrict__ W_in, unsigned short* __restrict__ W_in_t)
{
    const int bid = blockIdx.x;
    if (bid >= 4096) {
        const int i = (bid - 4096) * 256 + threadIdx.x;
        float4 v = ((const float4*)x)[i];
        ushort4 o = { f2bf(v.x), f2bf(v.y), f2bf(v.z), f2bf(v.w) };
        ((ushort4*)x_bf)[i] = o;
        return;
    }
    __shared__ float tile[32][33];
    const int K = 1024, N = 4096, t = bid;
    const int nx = N >> 5;
    const int n0 = (t % nx) * 32;
    const int k0 = (t / nx) * 32;
    const int c = threadIdx.x & 31;
    const int r = threadIdx.x >> 5;
#pragma unroll
    for (int i = 0; i < 4; ++i)
        tile[r + 8 * i][c] = W_in[(size_t)(k0 + r + 8 * i) * N + n0 + c];
    __syncthreads();
#pragma unroll
    for (int i = 0; i < 4; ++i)
        W_in_t[(size_t)(n0 + r + 8 * i) * K + k0 + c] = f2bf(tile[c][r + 8 * i]);
}

// ---------------------------------------------------------------------------
// bf16 MFMA GEMM — global_load_lds width-16 staging, swizzle folded into the
// per-lane global address (LDS linear, image identical to reg-staged layout).
// 2x2 waves, wave tile (TM/2)x(TN/2).
// NGEMM != 0: 1D grid; blocks >= NGEMM do folded side-work:
//   XW=0: 64x64 bf16 transpose tin [M][DINNER] -> tout [DINNER][M] (r11 fold)
//   XW=1: f32 weight transposes (W_dt 4096 tiles, then W_out 2048 tiles).
// RIDER OVERLAP REQUIREMENT (r12 lesson): gemm grid blocks/CU must be LESS
// than the co-residency cap (MINW), else riders serialize after the GEMM.
// gemm1: 512 blocks = 2/CU with MINW=4 -> 2 free slots/CU for riders.
// MODE 0: +bias; 1: softplus(+bias); 2: +bias+resid;
// 4: softplus(+bias) -> bf16 transposed Ct[col][row];
// 5: split: cols<DINNER -> f32 C; cols>=DINNER -> silu -> bf16 zout^T.
// ---------------------------------------------------------------------------
template <int TM, int TN, int MODE, int MINW, int NGEMM, int XW>
__global__ __launch_bounds__(256, MINW) void gemm_bf16(
    const unsigned short* __restrict__ A, const unsigned short* __restrict__ Bt,
    const float* __restrict__ bias, const float* __restrict__ resid,
    float* __restrict__ C, unsigned short* __restrict__ zout,
    const unsigned short* __restrict__ tin, unsigned short* __restrict__ tout,
    const float* __restrict__ ws1, unsigned short* __restrict__ wd1,
    const float* __restrict__ ws2, unsigned short* __restrict__ wd2,
    int M, int N, int K)
{
    constexpr int MI = TM / 32;
    constexpr int NJ = TN / 32;
    constexpr int NINSTR = (TM + TN) / 8;   // 8 rows (1 KB) per instr
    constexpr int NI = NINSTR / 4;          // instrs per wave

    __shared__ unsigned short As[TM * 64];
    __shared__ unsigned short Bs[TN * 64];

    const int tid  = threadIdx.x;

    if (NGEMM != 0 && (int)blockIdx.x >= NGEMM) {
        if (XW == 0) {
            // ---- bf16 transpose block: tin [M][DINNER] -> tout [DINNER][M] ----
            unsigned short (*tile)[66] = (unsigned short (*)[66])As;  // 8.4 KB <= As
            const int t = blockIdx.x - NGEMM;
            const int m0t = (t & 31) * 64;
            const int d0t = (t >> 5) * 64;
            const int r = tid >> 3;
            const int c = (tid & 7) * 8;
#pragma unroll
            for (int i = 0; i < 2; ++i) {
                const int row = r + i * 32;
                ushort8v v = *(const ushort8v*)&tin[(size_t)(m0t + row) * DINNER + d0t + c];
                *(ushort8v*)&tile[row][c] = v;
            }
            __syncthreads();
#pragma unroll
            for (int i = 0; i < 2; ++i) {
                const int dd = r + i * 32;
                ushort8v o;
#pragma unroll
                for (int k = 0; k < 8; ++k) o[k] = tile[c + k][dd];
                *(ushort8v*)&tout[(size_t)(d0t + dd) * (B_SZ * L_SEQ) + m0t + c] = o;
            }
        } else {
            // ---- f32 weight transpose block (prep fold): W_dt then W_out ----
            float (*tile)[33] = (float (*)[33])As;   // 4.2 KB <= As
            const int t0 = blockIdx.x - NGEMM;
            const float* W; unsigned short* Wt; int K2, N2, t;
            if (t0 < 4096) { W = ws1; Wt = wd1; K2 = 2048; N2 = 2048; t = t0; }
            else           { W = ws2; Wt = wd2; K2 = 2048; N2 = 1024; t = t0 - 4096; }
            const int nx2 = N2 >> 5;
            const int n0t = (t % nx2) * 32;
            const int k0t = (t / nx2) * 32;
            const int cc = tid & 31;
            const int rr = tid >> 5;
#pragma unroll
            for (int i = 0; i < 4; ++i)
                tile[rr + 8 * i][cc] = W[(size_t)(k0t + rr + 8 * i) * N2 + n0t + cc];
            __syncthreads();
#pragma unroll
            for (int i = 0; i < 4; ++i)
                Wt[(size_t)(n0t + rr + 8 * i) * K2 + k0t + cc] = f2bf(tile[cc][rr + 8 * i]);
        }
        return;
    }

    const int wave = tid >> 6;
    const int lane = tid & 63;
    const int nx = N / TN;
    const int m0 = (NGEMM != 0 ? (int)blockIdx.x / nx : (int)blockIdx.y) * TM;
    const int n0 = (NGEMM != 0 ? (int)blockIdx.x % nx : (int)blockIdx.x) * TN;
    const int wm = (wave >> 1) * (TM / 2);
    const int wn = (wave & 1) * (TN / 2);
    const int fr = lane & 15;
    const int kg = lane >> 4;

    // per-wave staging descriptors: global src per-lane (swizzled), LDS base uniform
    const unsigned short* gq[NI];
    unsigned short* lq[NI];
#pragma unroll
    for (int q = 0; q < NI; ++q) {
        const int idx = wave * NI + q;
        const int r0i = idx * 8;
        const int sub = lane >> 3;
        const int pos = lane & 7;
        if (r0i < TM) {
            const int row = r0i + sub;
            const int ch  = pos ^ (row & 7);
            gq[q] = A + (size_t)(m0 + row) * K + ch * 8;
            lq[q] = &As[r0i * 64];
        } else {
            const int rb = r0i - TM + sub;
            const int ch = pos ^ (rb & 7);
            gq[q] = Bt + (size_t)(n0 + rb) * K + ch * 8;
            lq[q] = &Bs[(r0i - TM) * 64];
        }
    }

    floatx4 acc[MI][NJ] = {};

#pragma unroll
    for (int q = 0; q < NI; ++q) gload_lds16(gq[q], lq[q]);

    for (int kt = 0; kt < K; kt += 64) {
        __syncthreads();   // vmcnt drained before barrier -> staging visible

#pragma unroll
        for (int ks = 0; ks < 2; ++ks) {
            const int cq = (ks << 2) | kg;
            bf16x8 af[MI], bfv[NJ];
#pragma unroll
            for (int i = 0; i < MI; ++i) {
                const int row = wm + i * 16 + fr;
                af[i] = *(const bf16x8*)&As[row * 64 + ((cq ^ (row & 7)) << 3)];
            }
#pragma unroll
            for (int j = 0; j < NJ; ++j) {
                const int row = wn + j * 16 + fr;
                bfv[j] = *(const bf16x8*)&Bs[row * 64 + ((cq ^ (row & 7)) << 3)];
            }
#pragma unroll
            for (int i = 0; i < MI; ++i)
#pragma unroll
                for (int j = 0; j < NJ; ++j)
                    acc[i][j] = __builtin_amdgcn_mfma_f32_16x16x32_bf16(
                        af[i], bfv[j], acc[i][j], 0, 0, 0);
        }

        if (kt + 64 < K) {
            __syncthreads();   // all reads done before overwrite
#pragma unroll
            for (int q = 0; q < NI; ++q) gload_lds16(gq[q] + kt + 64, lq[q]);
        }
    }

    const int rq = (lane >> 4) * 4;
    if (MODE == 4) {
        unsigned short* Ct = (unsigned short*)C;
#pragma unroll
        for (int i = 0; i < MI; ++i) {
#pragma unroll
            for (int j = 0; j < NJ; ++j) {
                const int col = n0 + wn + j * 16 + fr;
                const float bv = bias[col];
                const int row0 = m0 + wm + i * 16 + rq;
                ushort4 o;
#pragma unroll
                for (int r = 0; r < 4; ++r)
                    (&o.x)[r] = f2bf(softplus_f(acc[i][j][r] + bv));
                *(ushort4*)&Ct[(size_t)col * M + row0] = o;
            }
        }
    } else if (MODE == 5) {
        if (n0 < DINNER) {
#pragma unroll
            for (int i = 0; i < MI; ++i) {
#pragma unroll
                for (int j = 0; j < NJ; ++j) {
                    const int col = n0 + wn + j * 16 + fr;
                    const float bv = bias[col];
#pragma unroll
                    for (int r = 0; r < 4; ++r) {
                        const int row = m0 + wm + i * 16 + rq + r;
                        C[(size_t)row * DINNER + col] = acc[i][j][r] + bv;
                    }
                }
            }
        } else {
#pragma unroll
            for (int i = 0; i < MI; ++i) {
#pragma unroll
                for (int j = 0; j < NJ; ++j) {
                    const int col = n0 + wn + j * 16 + fr;
                    const float bv = bias[col];
                    const int row0 = m0 + wm + i * 16 + rq;
                    ushort4 o;
#pragma unroll
                    for (int r = 0; r < 4; ++r)
                        (&o.x)[r] = f2bf(silu_f(acc[i][j][r] + bv));
                    *(ushort4*)&zout[(size_t)(col - DINNER) * M + row0] = o;
                }
            }
        }
    } else {
#pragma unroll
        for (int i = 0; i < MI; ++i) {
#pragma unroll
            for (int j = 0; j < NJ; ++j) {
                const int col = n0 + wn + j * 16 + fr;
                const float bv = bias[col];
#pragma unroll
                for (int r = 0; r < 4; ++r) {
                    const int row = m0 + wm + i * 16 + rq + r;
                    float v = acc[i][j][r] + bv;
                    if (MODE == 1) {
                        v = softplus_f(v);
                    } else if (MODE == 2) {
                        v += resid[(size_t)row * N + col];
                    }
                    C[(size_t)row * N + col] = v;
                }
            }
        }
    }
}

// ---------------------------------------------------------------------------
// Fused depthwise causal conv1d(k=4) + SiLU + x_proj. bf16 x_conv only.
// ---------------------------------------------------------------------------
#define CROWS 4
__global__ __launch_bounds__(256) void conv_xproj(
    const float* __restrict__ x_in, const float* __restrict__ conv_w,
    const float* __restrict__ conv_b, const float* __restrict__ W_xp,
    const float* __restrict__ b_xp,
    unsigned short* __restrict__ x_conv_bf, float* __restrict__ BC)
{
    __shared__ float sxc[CROWS][DINNER];   // 32 KB
    __shared__ float red[8][CROWS][32];    // 4 KB

    const int tid = threadIdx.x;
    const int r0 = blockIdx.x * CROWS;
    const int c8 = tid * 8;

    float wt[8][4];
#pragma unroll
    for (int ci = 0; ci < 8; ++ci) {
        float4 w4 = *(const float4*)&conv_w[(c8 + ci) * 4];
        wt[ci][0] = w4.x; wt[ci][1] = w4.y; wt[ci][2] = w4.z; wt[ci][3] = w4.w;
    }
    float cb[8];
    *(float4*)&cb[0] = *(const float4*)&conv_b[c8];
    *(float4*)&cb[4] = *(const float4*)&conv_b[c8 + 4];

#pragma unroll
    for (int rr = 0; rr < CROWS; ++rr) {
        const int row = r0 + rr;
        const int l = row & (L_SEQ - 1);
        float acc[8];
#pragma unroll
        for (int ci = 0; ci < 8; ++ci) acc[ci] = cb[ci];
#pragma unroll
        for (int h = 0; h < 4; ++h) {
            const int lsrc = l - 3 + h;
            if (lsrc >= 0) {
                float4 a = *(const float4*)&x_in[(size_t)(row - 3 + h) * DINNER + c8];
                float4 b = *(const float4*)&x_in[(size_t)(row - 3 + h) * DINNER + c8 + 4];
                acc[0] += a.x * wt[0][h]; acc[1] += a.y * wt[1][h];
                acc[2] += a.z * wt[2][h]; acc[3] += a.w * wt[3][h];
                acc[4] += b.x * wt[4][h]; acc[5] += b.y * wt[5][h];
                acc[6] += b.z * wt[6][h]; acc[7] += b.w * wt[7][h];
            }
        }
        float o[8];
        ushort8v ob;
#pragma unroll
        for (int ci = 0; ci < 8; ++ci) {
            o[ci] = silu_f(acc[ci]);
            sxc[rr][c8 + ci] = o[ci];
            ob[ci] = (short)f2bf(o[ci]);
        }
        *(ushort8v*)&x_conv_bf[(size_t)row * DINNER + c8] = ob;
    }
    __syncthreads();

    const int n = tid & 31;
    const int g = tid >> 5;
    float p[CROWS] = {};
    const int k0 = g * 256;
#pragma unroll 4
    for (int k = k0; k < k0 + 256; ++k) {
        const float wv = W_xp[k * 32 + n];
        p[0] += sxc[0][k] * wv;
        p[1] += sxc[1][k] * wv;
        p[2] += sxc[2][k] * wv;
        p[3] += sxc[3][k] * wv;
    }
#pragma unroll
    for (int rr = 0; rr < CROWS; ++rr) red[g][rr][n] = p[rr];
    __syncthreads();
    if (tid < CROWS * 32) {
        const int rr = tid >> 5;
        const int n2 = tid & 31;
        float s = b_xp[n2];
#pragma unroll
        for (int gg = 0; gg < 8; ++gg) s += red[gg][rr][n2];
        BC[(size_t)(r0 + rr) * 32 + n2] = s;
    }
}

// ---------------------------------------------------------------------------
// Chunked two-pass selective scan (round-6 proven: DT=16/CCH=64, 37 KB LDS,
// conflict-free combine, all sequential inputs coalesced bf16x8 [D][B*L]).
// ---------------------------------------------------------------------------
__global__ __launch_bounds__(1024, 4) void scan_kernel(
    const unsigned short* __restrict__ deltaT,
    const unsigned short* __restrict__ xcT,
    const float* __restrict__ BC, const float* __restrict__ A_log,
    const float* __restrict__ D_skip, const unsigned short* __restrict__ zt,
    unsigned short* __restrict__ y_bf)
{
    __shared__ unsigned short sH[DSTATE * SSTR];   // 33.3 KB
    __shared__ float sDsum[CCH * DT];              // 4 KB

    const int tid = threadIdx.x;
    const int dl  = tid & (DT - 1);
    const int c   = tid >> 4;
    const int b   = blockIdx.x >> 7;
    const int d0  = (blockIdx.x & 127) * DT;
    const int d   = d0 + dl;

    const int l0 = c * CS;
    const int row0 = b * L_SEQ + l0;

    const unsigned short* dpt = deltaT + (size_t)d * (B_SZ * L_SEQ) + row0;
    bf16x8 dv0 = *(const bf16x8*)dpt;
    bf16x8 dv1 = *(const bf16x8*)(dpt + 8);
    const unsigned short* xpt = xcT + (size_t)d * (B_SZ * L_SEQ) + row0;
    bf16x8 xv0 = *(const bf16x8*)xpt;
    bf16x8 xv1 = *(const bf16x8*)(xpt + 8);
    const unsigned short* gpt = zt + (size_t)d * (B_SZ * L_SEQ) + row0;
    bf16x8 gv0 = *(const bf16x8*)gpt;
    bf16x8 gv1 = *(const bf16x8*)(gpt + 8);

    float Al[DSTATE];
#pragma unroll
    for (int s = 0; s < DSTATE; ++s)
        Al[s] = -__expf(A_log[d * DSTATE + s]) * 1.44269504f;
    const float Dsk = D_skip[d];

    float dts[CS], xcs[CS];
    float dsum = 0.f;
#pragma unroll
    for (int k = 0; k < 8; ++k) {
        dts[k]     = bf2f((unsigned short)dv0[k]);
        dts[8 + k] = bf2f((unsigned short)dv1[k]);
        xcs[k]     = bf2f((unsigned short)xv0[k]);
        xcs[8 + k] = bf2f((unsigned short)xv1[k]);
    }
#pragma unroll
    for (int k = 0; k < CS; ++k) dsum += dts[k];

    float h[DSTATE];
#pragma unroll
    for (int s = 0; s < DSTATE; ++s) h[s] = 0.f;

    const float* bcp = BC + (size_t)row0 * 32;

    // ---- pass 1: chunk summaries from h=0 ----
#pragma unroll 4
    for (int j = 0; j < CS; ++j) {
        const float dt = dts[j];
        const float xc = xcs[j];
        float Bv[DSTATE];
        *(float4*)&Bv[0]  = *(const float4*)(bcp + j * 32 + 0);
        *(float4*)&Bv[4]  = *(const float4*)(bcp + j * 32 + 4);
        *(float4*)&Bv[8]  = *(const float4*)(bcp + j * 32 + 8);
        *(float4*)&Bv[12] = *(const float4*)(bcp + j * 32 + 12);
        const float dlx = dt * xc;
#pragma unroll
        for (int s = 0; s < DSTATE; ++s) {
            const float e = nexp2(dt * Al[s]);
            h[s] = e * h[s] + dlx * Bv[s];
        }
    }
#pragma unroll
    for (int s = 0; s < DSTATE; ++s)
        sH[s * SSTR + tid] = f2bf(h[s]);
    sDsum[tid] = dsum;
    __syncthreads();

    // ---- combine: sequential over chunks, parallel over (s, dl) ----
    if (tid < DSTATE * DT) {
        const int dl2 = tid & (DT - 1);
        const int s2  = tid >> 4;
        const float Alc = -__expf(A_log[(d0 + dl2) * DSTATE + s2]) * 1.44269504f;
        float hh = 0.f;
        for (int c2 = 0; c2 < CCH; ++c2) {
            const int idx = s2 * SSTR + c2 * DT + dl2;
            const float a  = nexp2(Alc * sDsum[c2 * DT + dl2]);
            const float he = bf2f(sH[idx]);
            sH[idx] = f2bf(hh);
            hh = a * hh + he;
        }
    }
    __syncthreads();

#pragma unroll
    for (int s = 0; s < DSTATE; ++s) h[s] = bf2f(sH[s * SSTR + tid]);

    // ---- pass 2: rescan with true h0, fuse D_skip + precomputed gate ----
    unsigned short* yp = y_bf + (size_t)row0 * DINNER + d;
#pragma unroll
    for (int j = 0; j < 8; ++j) {
        const float dt = dts[j];
        const float xc = xcs[j];
        const float g  = bf2f((unsigned short)gv0[j]);
        float Bv[DSTATE], Cv[DSTATE];
        *(float4*)&Bv[0]  = *(const float4*)(bcp + j * 32 + 0);
        *(float4*)&Bv[4]  = *(const float4*)(bcp + j * 32 + 4);
        *(float4*)&Bv[8]  = *(const float4*)(bcp + j * 32 + 8);
        *(float4*)&Bv[12] = *(const float4*)(bcp + j * 32 + 12);
        *(float4*)&Cv[0]  = *(const float4*)(bcp + j * 32 + 16);
        *(float4*)&Cv[4]  = *(const float4*)(bcp + j * 32 + 20);
        *(float4*)&Cv[8]  = *(const float4*)(bcp + j * 32 + 24);
        *(float4*)&Cv[12] = *(const float4*)(bcp + j * 32 + 28);
        const float dlx = dt * xc;
        float y = Dsk * xc;
#pragma unroll
        for (int s = 0; s < DSTATE; ++s) {
            const float e = nexp2(dt * Al[s]);
            h[s] = e * h[s] + dlx * Bv[s];
            y += h[s] * Cv[s];
        }
        yp[j * DINNER] = f2bf(y * g);
    }
#pragma unroll
    for (int j2 = 0; j2 < 8; ++j2) {
        const int j = j2 + 8;
        const float dt = dts[j];
        const float xc = xcs[j];
        const float g  = bf2f((unsigned short)gv1[j2]);
        float Bv[DSTATE], Cv[DSTATE];
        *(float4*)&Bv[0]  = *(const float4*)(bcp + j * 32 + 0);
        *(float4*)&Bv[4]  = *(const float4*)(bcp + j * 32 + 4);
        *(float4*)&Bv[8]  = *(const float4*)(bcp + j * 32 + 8);
        *(float4*)&Bv[12] = *(const float4*)(bcp + j * 32 + 12);
        *(float4*)&Cv[0]  = *(const float4*)(bcp + j * 32 + 16);
        *(float4*)&Cv[4]  = *(const float4*)(bcp + j * 32 + 20);
        *(float4*)&Cv[8]  = *(const float4*)(bcp + j * 32 + 24);
        *(float4*)&Cv[12] = *(const float4*)(bcp + j * 32 + 28);
        const float dlx = dt * xc;
        float y = Dsk * xc;
#pragma unroll
        for (int s = 0; s < DSTATE; ++s) {
            const float e = nexp2(dt * Al[s]);
            h[s] = e * h[s] + dlx * Bv[s];
            y += h[s] * Cv[s];
        }
        yp[j * DINNER] = f2bf(y * g);
    }
}

// ---------------------------------------------------------------------------
// Row LayerNorm: unbiased variance (N-1), eps added to std.
// ---------------------------------------------------------------------------
__global__ __launch_bounds__(256) void layernorm_kernel(
    const float* __restrict__ t, const float* __restrict__ alpha,
    const float* __restrict__ beta, float* __restrict__ out)
{
    __shared__ float sred[4];
    __shared__ float sred2[4];
    const int row = blockIdx.x;
    const int tid = threadIdx.x;
    const float* r = t + (size_t)row * DMODEL;

    float4 v = *(const float4*)&r[tid * 4];
    float lsum = v.x + v.y + v.z + v.w;
#pragma unroll
    for (int m = 1; m < 64; m <<= 1) lsum += __shfl_xor(lsum, m);
    if ((tid & 63) == 0) sred[tid >> 6] = lsum;
    __syncthreads();
    const float mean = (sred[0] + sred[1] + sred[2] + sred[3]) * (1.f / DMODEL);

    const float dx = v.x - mean, dy = v.y - mean, dz = v.z - mean, dw = v.w - mean;
    float ls2 = dx * dx + dy * dy + dz * dz + dw * dw;
#pragma unroll
    for (int m = 1; m < 64; m <<= 1) ls2 += __shfl_xor(ls2, m);
    if ((tid & 63) == 0) sred2[tid >> 6] = ls2;
    __syncthreads();
    const float var = (sred2[0] + sred2[1] + sred2[2] + sred2[3]) * (1.f / (DMODEL - 1));
    const float inv = 1.f / (sqrtf(var) + EPSV);

    float4 a4 = *(const float4*)&alpha[tid * 4];
    float4 b4 = *(const float4*)&beta[tid * 4];
    float4 o;
    o.x = a4.x * dx * inv + b4.x;
    o.y = a4.y * dy * inv + b4.y;
    o.z = a4.z * dz * inv + b4.z;
    o.w = a4.w * dw * inv + b4.w;
    *(float4*)&out[(size_t)row * DMODEL + tid * 4] = o;
}

// ---------------------------------------------------------------------------
extern "C" void kernel_launch(void* const* d_in, const int* in_sizes, int n_in,
                              void* d_out, int out_size, void* d_ws, size_t ws_size,
                              hipStream_t stream)
{
    const float* x      = (const float*)d_in[0];
    const float* W_in   = (const float*)d_in[1];
    const float* b_in   = (const float*)d_in[2];
    const float* conv_w = (const float*)d_in[3];
    const float* conv_b = (const float*)d_in[4];
    const float* W_xp   = (const float*)d_in[5];
    const float* b_xp   = (const float*)d_in[6];
    const float* W_dt   = (const float*)d_in[7];
    const float* b_dt   = (const float*)d_in[8];
    const float* A_log  = (const float*)d_in[9];
    const float* D_skip = (const float*)d_in[10];
    const float* W_out  = (const float*)d_in[11];
    const float* b_out  = (const float*)d_in[12];
    const float* alpha  = (const float*)d_in[13];
    const float* beta   = (const float*)d_in[14];
    float* out = (float*)d_out;

    const size_t M = (size_t)B_SZ * L_SEQ;  // 2048 rows
    char* ws = (char*)d_ws;
    float* x_in    = (float*)(ws + 0);                  // 16 MB (reused as tpre)
    unsigned short* zt = (unsigned short*)(ws + (16u << 20));      // 8 MB, [D][B*L]
    unsigned short* deltaT = (unsigned short*)(ws + (48u << 20));  // 8 MB, [D][B*L]
    float* BC      = (float*)(ws + (64u << 20));        // 0.5 MB
    unsigned short* x_bf       = (unsigned short*)(ws + (64u << 20) + (512u << 10)); // 4 MB
    unsigned short* W_in_t     = (unsigned short*)(ws + (69u << 20));  // 8 MB
    unsigned short* W_dt_t     = (unsigned short*)(ws + (77u << 20));  // 8 MB
    unsigned short* W_out_t    = (unsigned short*)(ws + (85u << 20));  // 4 MB
    unsigned short* x_conv_bf  = (unsigned short*)(ws + (89u << 20));  // 8 MB
    unsigned short* xcT        = (unsigned short*)(ws + (24u << 20));  // 8 MB, [D][B*L]
    unsigned short* ygate_bf   = (unsigned short*)(ws + (77u << 20));  // reuse W_dt_t
    float* tpre = x_in;

    const dim3 blk(256);

    // 0. prep (shrunk): W_in transpose + x cast only (6144 blocks)
    prep_kernel<<<dim3(6144), blk, 0, stream>>>(x, x_bf, W_in, W_in_t);

    // 1. xz = x @ W_in + b_in (2048 x 4096 x 1024), 128x128, MINW=4:
    //    512 GEMM blocks = 2/CU leaves 2 free slots/CU so the 6144 rider
    //    blocks (W_dt^T, W_out^T) genuinely co-reside (r12 lesson).
    gemm_bf16<128, 128, 5, 4, 512, 1><<<dim3(512 + 6144), blk, 0, stream>>>(
        x_bf, W_in_t, b_in, nullptr, x_in, zt, nullptr, nullptr,
        W_dt, W_dt_t, W_out, W_out_t, 2048, 4096, 1024);

    // 2+3. conv + SiLU + x_proj (fused)
    conv_xproj<<<dim3((unsigned)(M / CROWS)), blk, 0, stream>>>(
        x_in, conv_w, conv_b, W_xp, b_xp, x_conv_bf, BC);

    // 4. deltaT = softplus(x_conv @ W_dt + b_dt)^T -> bf16 [D][B*L], 128x64
    //    + 1024 rider blocks: x_conv [M][D] -> xcT [D][M] (r11-proven fold)
    gemm_bf16<128, 64, 4, 3, 512, 0><<<dim3(512 + 1024), blk, 0, stream>>>(
        x_conv_bf, W_dt_t, b_dt, nullptr, (float*)deltaT, nullptr,
        x_conv_bf, xcT, nullptr, nullptr, nullptr, nullptr, 2048, 2048, 2048);

    // 5. chunked two-pass selective scan + D_skip + gate -> bf16
    scan_kernel<<<dim3(B_SZ * (DINNER / DT)), dim3(1024), 0, stream>>>(
        deltaT, xcT, BC, A_log, D_skip, zt, ygate_bf);

    // 6. tpre = ygate @ W_out + b_out + x  (2048 x 1024 x 2048), 64x64 (r4 best)
    gemm_bf16<64, 64, 2, 3, 0, 0><<<dim3(1024 / 64, 2048 / 64), blk, 0, stream>>>(
        ygate_bf, W_out_t, b_out, x, tpre, nullptr, nullptr, nullptr,
        nullptr, nullptr, nullptr, nullptr, 2048, 1024, 2048);

    // 7. LayerNorm
    layernorm_kernel<<<dim3((unsigned)M), blk, 0, stream>>>(tpre, alpha, beta, out);
}